// Round 5
// baseline (534.133 us; speedup 1.0000x reference)
//
#include <hip/hip_runtime.h>

typedef float f32x4 __attribute__((ext_vector_type(4)));
typedef short s16x8 __attribute__((ext_vector_type(8)));

static constexpr int NTOK = 16384;   // B*S
static constexpr int D    = 256;
static constexpr int H    = 1024;
static constexpr int E    = 8;

__device__ __forceinline__ unsigned short f2bf(float f) {
    unsigned int u = __float_as_uint(f);
    u += 0x7FFFu + ((u >> 16) & 1u);   // round-to-nearest-even
    return (unsigned short)(u >> 16);
}
__device__ __forceinline__ s16x8 pack8(float4 a, float4 b) {
    s16x8 v;
    v[0] = (short)f2bf(a.x); v[1] = (short)f2bf(a.y);
    v[2] = (short)f2bf(a.z); v[3] = (short)f2bf(a.w);
    v[4] = (short)f2bf(b.x); v[5] = (short)f2bf(b.y);
    v[6] = (short)f2bf(b.z); v[7] = (short)f2bf(b.w);
    return v;
}

// ---------------- router: softmax, probs output (fp32), top-2 renorm, per-expert lists ----------------
__global__ void __launch_bounds__(256) router_kernel(
    const float* __restrict__ x,          // [NTOK][D] fp32
    const float* __restrict__ wr,         // [D][E]    fp32
    const float* __restrict__ br,         // [E]       fp32
    float* __restrict__ probs_out,        // [NTOK][E] fp32
    int* __restrict__ cnt, int* __restrict__ list, float* __restrict__ wlist)
{
    __shared__ float wrs[D][E];
    const int tid = threadIdx.x;
    {
        float4 a = *reinterpret_cast<const float4*>(wr + tid * 8);
        float4 b = *reinterpret_cast<const float4*>(wr + tid * 8 + 4);
        wrs[tid][0] = a.x; wrs[tid][1] = a.y; wrs[tid][2] = a.z; wrs[tid][3] = a.w;
        wrs[tid][4] = b.x; wrs[tid][5] = b.y; wrs[tid][6] = b.z; wrs[tid][7] = b.w;
    }
    __syncthreads();

    const int t = blockIdx.x * 256 + tid;
    float lg[8];
    #pragma unroll
    for (int e = 0; e < 8; ++e) lg[e] = br[e];

    const float* xr = x + (size_t)t * D;
    for (int d0 = 0; d0 < D; d0 += 4) {
        float4 xv = *reinterpret_cast<const float4*>(xr + d0);
        #pragma unroll
        for (int j = 0; j < 4; ++j) {
            const float xf = (j == 0) ? xv.x : (j == 1) ? xv.y : (j == 2) ? xv.z : xv.w;
            #pragma unroll
            for (int e = 0; e < 8; ++e) lg[e] += xf * wrs[d0 + j][e];
        }
    }
    float mx = lg[0];
    #pragma unroll
    for (int e = 1; e < 8; ++e) mx = fmaxf(mx, lg[e]);
    float p[8], s = 0.f;
    #pragma unroll
    for (int e = 0; e < 8; ++e) { p[e] = expf(lg[e] - mx); s += p[e]; }
    const float inv = 1.f / s;
    #pragma unroll
    for (int e = 0; e < 8; ++e) { p[e] *= inv; probs_out[t * 8 + e] = p[e]; }

    int i1 = 0;
    #pragma unroll
    for (int e = 1; e < 8; ++e) if (p[e] > p[i1]) i1 = e;       // strict > : lowest index wins
    int i2 = (i1 == 0) ? 1 : 0;
    #pragma unroll
    for (int e = 0; e < 8; ++e) if (e != i1 && p[e] > p[i2]) i2 = e;

    const float sw = p[i1] + p[i2];
    const float wa = p[i1] / sw, wb = p[i2] / sw;
    int pos = atomicAdd(&cnt[i1], 1);
    list[i1 * NTOK + pos] = t; wlist[i1 * NTOK + pos] = wa;
    pos = atomicAdd(&cnt[i2], 1);
    list[i2 * NTOK + pos] = t; wlist[i2 * NTOK + pos] = wb;
}

// ---------------- fused expert FFN: gather 64 tokens, X@W1 -> gelu -> Yt = W2^T@H^T, fp32 scatter-add ----------------
// fp32 weights staged from native layouts (w1 [E,D,H], w2 [E,H,D]): load float4x2 -> bf16 -> 8x8 register transpose.
__global__ void __launch_bounds__(256) expert_kernel(
    const float* __restrict__ x,          // [NTOK][D] fp32
    const float* __restrict__ w1,         // [E][D][H] fp32
    const float* __restrict__ w2,         // [E][H][D] fp32
    const float* __restrict__ b1,         // [E][H]    fp32
    const float* __restrict__ b2,         // [E][D]    fp32
    const int* __restrict__ cnt, const int* __restrict__ list,
    const float* __restrict__ wlist,
    float* __restrict__ out)              // [NTOK][D] fp32 (zeroed)
{
    const int e = blockIdx.y;
    int n = cnt[e]; n = (n < 0) ? 0 : ((n > NTOK) ? NTOK : n);
    const int tile0 = blockIdx.x * 64;
    if (tile0 >= n) return;
    const int nvalid = (n - tile0 < 64) ? (n - tile0) : 64;

    __shared__ __align__(16) unsigned short Xs [64 * 264];  // [64 tok][256 d +8]
    __shared__ __align__(16) unsigned short W1s[64 * 264];  // [64 h  ][256 d +8]   W1^T chunk
    __shared__ __align__(16) unsigned short W2s[256 * 72];  // [256 d ][64 h +8]    W2^T chunk, h-blocks XOR-swizzled
    __shared__ __align__(16) unsigned short Hs [64 * 72];   // [64 tok][64 h +8]
    __shared__ int   toks[64];
    __shared__ float wgts[64];

    const int tid  = threadIdx.x;
    const int lane = tid & 63;
    const int wv   = tid >> 6;    // wave 0..3
    const int mrow = lane & 15;
    const int kb   = lane >> 4;   // 0..3

    if (tid < 64) {
        if (tid < nvalid) {
            int tok = list[e * NTOK + tile0 + tid];
            toks[tid] = tok & 0x3FFF;
            wgts[tid] = wlist[e * NTOK + tile0 + tid];
        } else { toks[tid] = 0; wgts[tid] = 0.f; }
    }
    __syncthreads();

    // gather X rows into LDS as bf16 (invalid rows -> zeros)
    #pragma unroll
    for (int r = 0; r < 8; ++r) {
        int v = r * 256 + tid;
        int row = v >> 5, c8 = v & 31;
        s16x8 val = {0,0,0,0,0,0,0,0};
        if (row < nvalid) {
            const float* src = x + (size_t)toks[row] * D + c8 * 8;
            val = pack8(*reinterpret_cast<const float4*>(src),
                        *reinterpret_cast<const float4*>(src + 4));
        }
        *reinterpret_cast<s16x8*>(&Xs[row * 264 + c8 * 8]) = val;
    }

    f32x4 accYt[16];    // Yt: lane holds d=db*16+kb*4+r (row), t=wv*16+mrow (col)
    #pragma unroll
    for (int i = 0; i < 16; ++i) accYt[i] = (f32x4){0.f, 0.f, 0.f, 0.f};

    const int wr2 = wv >> 1, wc2 = wv & 1;
    // staging thread mappings
    const int hgrp  = tid & 7,  dblk  = tid >> 3;   // W1: 8 h-cols x 32 d-blocks
    const int dgrp  = tid & 31, hblk8 = tid >> 5;   // W2: 32 d-blocks x 8 h-blocks

    for (int hc = 0; hc < 16; ++hc) {
        __syncthreads();   // protects W1s/W2s/Hs reuse; also covers initial Xs/toks writes

        // ---- stage W1 chunk: W1s[h][d] = bf16(w1[e][d][hc*64+h]), 8x8 register transpose ----
        {
            s16x8 Y8[8];
            #pragma unroll
            for (int i = 0; i < 8; ++i) {
                const float* src = w1 + ((size_t)(e * D + dblk * 8 + i)) * H + hc * 64 + hgrp * 8;
                Y8[i] = pack8(*reinterpret_cast<const float4*>(src),
                              *reinterpret_cast<const float4*>(src + 4));
            }
            #pragma unroll
            for (int j = 0; j < 8; ++j) {
                s16x8 V;
                #pragma unroll
                for (int i = 0; i < 8; ++i) V[i] = Y8[i][j];
                *reinterpret_cast<s16x8*>(&W1s[(hgrp * 8 + j) * 264 + dblk * 8]) = V;
            }
        }
        // ---- stage W2 chunk: W2s[d][h'] = bf16(w2[e][hc*64+h][d]), h-block swizzled by (dgrp&7) ----
        {
            s16x8 Z8[8];
            #pragma unroll
            for (int i = 0; i < 8; ++i) {
                const float* src = w2 + ((size_t)(e * H + hc * 64 + hblk8 * 8 + i)) * D + dgrp * 8;
                Z8[i] = pack8(*reinterpret_cast<const float4*>(src),
                              *reinterpret_cast<const float4*>(src + 4));
            }
            const int hswz = (hblk8 ^ (dgrp & 7)) << 3;
            #pragma unroll
            for (int j = 0; j < 8; ++j) {
                s16x8 V;
                #pragma unroll
                for (int i = 0; i < 8; ++i) V[i] = Z8[i][j];
                *reinterpret_cast<s16x8*>(&W2s[(dgrp * 8 + j) * 72 + hswz]) = V;
            }
        }
        __syncthreads();

        // stage 1: Htile[64][64] = gelu(X @ W1chunk + b1); wave -> 2x2 of 16x16 tiles
        f32x4 accH[2][2];
        #pragma unroll
        for (int i = 0; i < 2; ++i)
            #pragma unroll
            for (int j = 0; j < 2; ++j)
                accH[i][j] = (f32x4){0.f, 0.f, 0.f, 0.f};
        #pragma unroll
        for (int ks = 0; ks < 8; ++ks) {
            const int koff = ks * 32 + kb * 8;
            s16x8 a0 = *reinterpret_cast<const s16x8*>(&Xs [((wr2*2+0)*16 + mrow)*264 + koff]);
            s16x8 a1 = *reinterpret_cast<const s16x8*>(&Xs [((wr2*2+1)*16 + mrow)*264 + koff]);
            s16x8 b0 = *reinterpret_cast<const s16x8*>(&W1s[((wc2*2+0)*16 + mrow)*264 + koff]);
            s16x8 b1v= *reinterpret_cast<const s16x8*>(&W1s[((wc2*2+1)*16 + mrow)*264 + koff]);
            accH[0][0] = __builtin_amdgcn_mfma_f32_16x16x32_bf16(a0, b0,  accH[0][0], 0, 0, 0);
            accH[0][1] = __builtin_amdgcn_mfma_f32_16x16x32_bf16(a0, b1v, accH[0][1], 0, 0, 0);
            accH[1][0] = __builtin_amdgcn_mfma_f32_16x16x32_bf16(a1, b0,  accH[1][0], 0, 0, 0);
            accH[1][1] = __builtin_amdgcn_mfma_f32_16x16x32_bf16(a1, b1v, accH[1][1], 0, 0, 0);
        }
        #pragma unroll
        for (int i = 0; i < 2; ++i)
            #pragma unroll
            for (int j = 0; j < 2; ++j) {
                const int hloc = (wc2*2 + j) * 16 + mrow;
                const float bias = b1[e * H + hc * 64 + hloc];
                #pragma unroll
                for (int r = 0; r < 4; ++r) {
                    const int m = (wr2*2 + i) * 16 + kb * 4 + r;   // C row = (lane>>4)*4+reg
                    float vvf = accH[i][j][r] + bias;
                    float g = 0.5f * vvf * (1.0f + erff(vvf * 0.70710678118654752f));
                    Hs[m * 72 + hloc] = f2bf(g);
                }
            }
        __syncthreads();

        // stage 2 (transposed): Yt[d][t] += sum_h W2s[d][h] * Hs[t][h]
        #pragma unroll
        for (int ks = 0; ks < 2; ++ks) {
            const int koff = ks * 32 + kb * 8;
            s16x8 bfrag = *reinterpret_cast<const s16x8*>(&Hs[(wv * 16 + mrow) * 72 + koff]);
            #pragma unroll
            for (int db = 0; db < 16; ++db) {
                const int arow = db * 16 + mrow;
                const int akey = (arow >> 3) & 7;
                s16x8 afrag = *reinterpret_cast<const s16x8*>(
                    &W2s[arow * 72 + (((ks * 4 + kb) ^ akey) << 3)]);
                accYt[db] = __builtin_amdgcn_mfma_f32_16x16x32_bf16(afrag, bfrag, accYt[db], 0, 0, 0);
            }
        }
    }

    // epilogue: out[t][d] += w * (y + b2), native fp32 atomics (d = db*16 + kb*4 + r, t = wv*16 + mrow)
    {
        const int t = wv * 16 + mrow;
        if (t < nvalid) {
            const float wt = wgts[t];
            float* obase = out + (size_t)toks[t] * D;
            #pragma unroll
            for (int db = 0; db < 16; ++db) {
                const int d0 = db * 16 + kb * 4;
                atomicAdd(obase + d0 + 0, (accYt[db][0] + b2[e * D + d0 + 0]) * wt);
                atomicAdd(obase + d0 + 1, (accYt[db][1] + b2[e * D + d0 + 1]) * wt);
                atomicAdd(obase + d0 + 2, (accYt[db][2] + b2[e * D + d0 + 2]) * wt);
                atomicAdd(obase + d0 + 3, (accYt[db][3] + b2[e * D + d0 + 3]) * wt);
            }
        }
    }
}

extern "C" void kernel_launch(void* const* d_in, const int* in_sizes, int n_in,
                              void* d_out, int out_size, void* d_ws, size_t ws_size,
                              hipStream_t stream)
{
    const float* x  = (const float*)d_in[0];
    const float* wr = (const float*)d_in[1];
    const float* br = (const float*)d_in[2];
    const float* w1 = (const float*)d_in[3];
    const float* b1 = (const float*)d_in[4];
    const float* w2 = (const float*)d_in[5];
    const float* b2 = (const float*)d_in[6];
    float* out = (float*)d_out;                 // [NTOK][D] fp32, then [NTOK][E] fp32 probs

    // workspace: 1,048,832 B total
    char* ws = (char*)d_ws;
    int*   cnt   = (int*)ws;                    //     256 B (8 used)
    int*   list  = (int*)(ws + 256);            // 524,288 B  [E][NTOK]
    float* wlist = (float*)(ws + 524544);       // 524,288 B  [E][NTOK]

    hipMemsetAsync(out, 0, (size_t)NTOK * D * 4, stream);   // expert kernel accumulates into out
    hipMemsetAsync(cnt, 0, 256, stream);
    router_kernel<<<64, 256, 0, stream>>>(x, wr, br, out + (size_t)NTOK * D, cnt, list, wlist);
    expert_kernel<<<dim3(256, 8), 256, 0, stream>>>(x, w1, w2, b1, b2, cnt, list, wlist, out);
}

// Round 6
// 464.960 us; speedup vs baseline: 1.1488x; 1.1488x over previous
//
#include <hip/hip_runtime.h>

typedef float f32x4 __attribute__((ext_vector_type(4)));
typedef short s16x8 __attribute__((ext_vector_type(8)));

static constexpr int NTOK = 16384;   // B*S
static constexpr int D    = 256;
static constexpr int H    = 1024;
static constexpr int E    = 8;

__device__ __forceinline__ unsigned short f2bf(float f) {
    unsigned int u = __float_as_uint(f);
    u += 0x7FFFu + ((u >> 16) & 1u);   // round-to-nearest-even
    return (unsigned short)(u >> 16);
}
__device__ __forceinline__ s16x8 pack8(float4 a, float4 b) {
    s16x8 v;
    v[0] = (short)f2bf(a.x); v[1] = (short)f2bf(a.y);
    v[2] = (short)f2bf(a.z); v[3] = (short)f2bf(a.w);
    v[4] = (short)f2bf(b.x); v[5] = (short)f2bf(b.y);
    v[6] = (short)f2bf(b.z); v[7] = (short)f2bf(b.w);
    return v;
}

// ---------------- one-time weight convert+transpose: fp32 -> bf16 ----------------
// w1 [E,D,H] -> w1t [E,H,D] bf16 ; w2 [E,H,D] -> w2t [E,D,H] bf16
__global__ void __launch_bounds__(256) convert_kernel(
    const float* __restrict__ w1, const float* __restrict__ w2,
    unsigned short* __restrict__ w1t, unsigned short* __restrict__ w2t)
{
    __shared__ unsigned short tile[32][33];
    int b = blockIdx.x;
    const float* src; unsigned short* dst;
    int Rr, Cc, tr, tc;
    if (b < 2048) {                      // w1: [256][1024] per expert
        int e = b >> 8, tt = b & 255;
        Rr = 256; Cc = 1024; tr = tt >> 5; tc = tt & 31;
        src = w1 + (size_t)e * Rr * Cc; dst = w1t + (size_t)e * Rr * Cc;
    } else {                             // w2: [1024][256] per expert
        b -= 2048;
        int e = b >> 8, tt = b & 255;
        Rr = 1024; Cc = 256; tr = tt >> 3; tc = tt & 7;
        src = w2 + (size_t)e * Rr * Cc; dst = w2t + (size_t)e * Rr * Cc;
    }
    const int tid = threadIdx.x;
    const int c = tid & 31, r0 = tid >> 5;
    #pragma unroll
    for (int rr = 0; rr < 32; rr += 8)
        tile[r0 + rr][c] = f2bf(src[(size_t)(tr * 32 + r0 + rr) * Cc + tc * 32 + c]);
    __syncthreads();
    #pragma unroll
    for (int rr = 0; rr < 32; rr += 8)
        dst[(size_t)(tc * 32 + r0 + rr) * Rr + tr * 32 + c] = tile[c][r0 + rr];
}

// ---------------- router: 16 lanes per token, coalesced, shfl-reduce ----------------
__global__ void __launch_bounds__(256) router_kernel(
    const float* __restrict__ x,          // [NTOK][D] fp32
    const float* __restrict__ wr,         // [D][E]    fp32
    const float* __restrict__ br,         // [E]       fp32
    float* __restrict__ probs_out,        // [NTOK][E] fp32
    int* __restrict__ cnt, int* __restrict__ list, float* __restrict__ wlist)
{
    __shared__ float wrs[D][E];
    const int tid = threadIdx.x;
    {
        float4 a = *reinterpret_cast<const float4*>(wr + tid * 8);
        float4 b = *reinterpret_cast<const float4*>(wr + tid * 8 + 4);
        wrs[tid][0] = a.x; wrs[tid][1] = a.y; wrs[tid][2] = a.z; wrs[tid][3] = a.w;
        wrs[tid][4] = b.x; wrs[tid][5] = b.y; wrs[tid][6] = b.z; wrs[tid][7] = b.w;
    }
    __syncthreads();

    const int g = tid >> 4, l = tid & 15;            // 16 tokens/block, 16 lanes/token
    const int t = blockIdx.x * 16 + g;

    float lg[8];
    #pragma unroll
    for (int e = 0; e < 8; ++e) lg[e] = 0.f;

    const float* xr = x + (size_t)t * D;
    #pragma unroll
    for (int r = 0; r < 4; ++r) {
        const int d = r * 64 + l * 4;
        float4 xv = *reinterpret_cast<const float4*>(xr + d);
        #pragma unroll
        for (int j = 0; j < 4; ++j) {
            const float xf = (j == 0) ? xv.x : (j == 1) ? xv.y : (j == 2) ? xv.z : xv.w;
            #pragma unroll
            for (int e = 0; e < 8; ++e) lg[e] += xf * wrs[d + j][e];
        }
    }
    // reduce across the 16-lane group
    #pragma unroll
    for (int off = 1; off < 16; off <<= 1)
        #pragma unroll
        for (int e = 0; e < 8; ++e) lg[e] += __shfl_xor(lg[e], off, 16);

    if (l == 0) {
        #pragma unroll
        for (int e = 0; e < 8; ++e) lg[e] += br[e];
        float mx = lg[0];
        #pragma unroll
        for (int e = 1; e < 8; ++e) mx = fmaxf(mx, lg[e]);
        float p[8], s = 0.f;
        #pragma unroll
        for (int e = 0; e < 8; ++e) { p[e] = expf(lg[e] - mx); s += p[e]; }
        const float inv = 1.f / s;
        #pragma unroll
        for (int e = 0; e < 8; ++e) p[e] *= inv;
        float4 o0 = {p[0], p[1], p[2], p[3]}, o1 = {p[4], p[5], p[6], p[7]};
        *reinterpret_cast<float4*>(probs_out + t * 8)     = o0;
        *reinterpret_cast<float4*>(probs_out + t * 8 + 4) = o1;

        int i1 = 0;
        #pragma unroll
        for (int e = 1; e < 8; ++e) if (p[e] > p[i1]) i1 = e;   // strict > : lowest index wins
        int i2 = (i1 == 0) ? 1 : 0;
        #pragma unroll
        for (int e = 0; e < 8; ++e) if (e != i1 && p[e] > p[i2]) i2 = e;
        const float sw = p[i1] + p[i2];
        int pos = atomicAdd(&cnt[i1], 1);
        list[i1 * NTOK + pos] = t; wlist[i1 * NTOK + pos] = p[i1] / sw;
        pos = atomicAdd(&cnt[i2], 1);
        list[i2 * NTOK + pos] = t; wlist[i2 * NTOK + pos] = p[i2] / sw;
    }
}

// ---------------- expert FFN v2: 512 threads, bf16 weights, swizzled LDS, pipelined ----------------
__global__ void __launch_bounds__(512) expert_kernel_v2(
    const float* __restrict__ x,              // [NTOK][D] fp32
    const unsigned short* __restrict__ w1t,   // [E][H][D] bf16
    const unsigned short* __restrict__ w2t,   // [E][D][H] bf16
    const float* __restrict__ b1,             // [E][H]
    const float* __restrict__ b2,             // [E][D]
    const int* __restrict__ cnt, const int* __restrict__ list,
    const float* __restrict__ wlist,
    float* __restrict__ out)                  // [NTOK][D] fp32 (zeroed)
{
    const int e = blockIdx.y;
    int n = cnt[e]; n = (n < 0) ? 0 : ((n > NTOK) ? NTOK : n);
    const int tile0 = blockIdx.x * 64;
    if (tile0 >= n) return;
    const int nvalid = (n - tile0 < 64) ? (n - tile0) : 64;

    __shared__ __align__(16) unsigned short Xs [64 * 256];  // [tok][d]  swizzled, no pad
    __shared__ __align__(16) unsigned short W1s[64 * 256];  // [h][d]    swizzled
    __shared__ __align__(16) unsigned short W2s[256 * 64];  // [d][h]    swizzled
    __shared__ __align__(16) unsigned short Hs [64 * 64];   // [tok][h]  swizzled
    __shared__ int   toks[64];
    __shared__ float wgts[64];

    const int tid  = threadIdx.x;
    const int lane = tid & 63;
    const int wv   = tid >> 6;          // 0..7
    const int mrow = lane & 15;
    const int kb   = lane >> 4;         // 0..3
    const int key  = mrow & 7;          // swizzle key for all MFMA-phase accesses
    const int rb   = wv & 3;            // stage1 token row-block
    const int ch   = wv >> 2;           // stage1 h col-half
    const int tg   = wv & 3;            // stage2 token group
    const int dh   = wv >> 2;           // stage2 d half

    if (tid < 64) {
        if (tid < nvalid) {
            toks[tid] = list[e * NTOK + tile0 + tid] & 0x3FFF;
            wgts[tid] = wlist[e * NTOK + tile0 + tid];
        } else { toks[tid] = 0; wgts[tid] = 0.f; }
    }
    __syncthreads();

    // gather X rows into LDS as bf16, swizzled (invalid rows -> zeros)
    #pragma unroll
    for (int k = 0; k < 4; ++k) {
        const int s = k * 512 + tid;
        const int row = s >> 5, c = s & 31;
        s16x8 val = {0,0,0,0,0,0,0,0};
        if (row < nvalid) {
            const float* src = x + (size_t)toks[row] * D + c * 8;
            val = pack8(*reinterpret_cast<const float4*>(src),
                        *reinterpret_cast<const float4*>(src + 4));
        }
        *reinterpret_cast<s16x8*>(&Xs[row * 256 + ((c ^ (row & 7)) << 3)]) = val;
    }

    // weight prefetch registers
    s16x8 pfW1[4], pfW2[4];
    const size_t w1b = (size_t)e * H * D;
    const size_t w2b = (size_t)e * D * H;

    #define LOADW(HC)                                                              \
        _Pragma("unroll")                                                          \
        for (int k = 0; k < 4; ++k) {                                              \
            const int s1 = k * 512 + tid, h1 = s1 >> 5, c1 = s1 & 31;              \
            pfW1[k] = *reinterpret_cast<const s16x8*>(                             \
                w1t + w1b + (size_t)((HC) * 64 + h1) * D + c1 * 8);                \
            const int s2 = k * 512 + tid, d2 = s2 >> 3, c2 = s2 & 7;               \
            pfW2[k] = *reinterpret_cast<const s16x8*>(                             \
                w2t + w2b + (size_t)d2 * H + (HC) * 64 + c2 * 8);                  \
        }
    #define STOREW()                                                               \
        _Pragma("unroll")                                                          \
        for (int k = 0; k < 4; ++k) {                                              \
            const int s1 = k * 512 + tid, h1 = s1 >> 5, c1 = s1 & 31;              \
            *reinterpret_cast<s16x8*>(&W1s[h1 * 256 + ((c1 ^ (h1 & 7)) << 3)]) = pfW1[k]; \
            const int s2 = k * 512 + tid, d2 = s2 >> 3, c2 = s2 & 7;               \
            *reinterpret_cast<s16x8*>(&W2s[d2 * 64 + ((c2 ^ (d2 & 7)) << 3)]) = pfW2[k];  \
        }

    LOADW(0);
    __syncthreads();          // Xs writes complete before W-store phase (shared fence)
    STOREW();
    LOADW(1);

    f32x4 accYt[8];           // stage2: d = (dh*8+db)*16 + kb*4 + r, t = tg*16 + mrow
    #pragma unroll
    for (int i = 0; i < 8; ++i) accYt[i] = (f32x4){0.f, 0.f, 0.f, 0.f};

    __syncthreads();          // W1s/W2s chunk0 visible

    for (int hc = 0; hc < 16; ++hc) {
        // ---- stage 1: accH = X(rb) @ W1chunk(ch) ----
        f32x4 accH[2];
        accH[0] = (f32x4){0.f, 0.f, 0.f, 0.f};
        accH[1] = (f32x4){0.f, 0.f, 0.f, 0.f};
        const int arow = rb * 16 + mrow;
        const int h0   = ch * 32 + mrow;
        #pragma unroll
        for (int ks = 0; ks < 8; ++ks) {
            const int c = ks * 4 + kb;
            const int sc = (c ^ key) << 3;
            s16x8 a  = *reinterpret_cast<const s16x8*>(&Xs [arow * 256 + sc]);
            s16x8 b0 = *reinterpret_cast<const s16x8*>(&W1s[h0 * 256 + sc]);
            s16x8 b1f= *reinterpret_cast<const s16x8*>(&W1s[(h0 + 16) * 256 + sc]);
            accH[0] = __builtin_amdgcn_mfma_f32_16x16x32_bf16(a, b0,  accH[0], 0, 0, 0);
            accH[1] = __builtin_amdgcn_mfma_f32_16x16x32_bf16(a, b1f, accH[1], 0, 0, 0);
        }
        // gelu -> Hs (scalar u16, swizzled)
        #pragma unroll
        for (int j = 0; j < 2; ++j) {
            const int hcol = ch * 32 + j * 16 + mrow;
            const float bias = b1[e * H + hc * 64 + hcol];
            const int hblk = hcol >> 3, hlo = hcol & 7;
            #pragma unroll
            for (int r = 0; r < 4; ++r) {
                const int t = rb * 16 + kb * 4 + r;
                const float vvf = accH[j][r] + bias;
                const float g = 0.5f * vvf * (1.0f + erff(vvf * 0.70710678118654752f));
                Hs[t * 64 + ((hblk ^ (t & 7)) << 3) + hlo] = f2bf(g);
            }
        }
        __syncthreads();      // Hs visible

        // ---- stage 2: accYt += W2chunk^T-tiles @ H^T ----
        const int tloc = tg * 16 + mrow;
        #pragma unroll
        for (int ks = 0; ks < 2; ++ks) {
            const int c = ks * 4 + kb;
            const int sc = (c ^ key) << 3;
            s16x8 bfrag = *reinterpret_cast<const s16x8*>(&Hs[tloc * 64 + sc]);
            #pragma unroll
            for (int db = 0; db < 8; ++db) {
                const int d = (dh * 8 + db) * 16 + mrow;
                s16x8 afrag = *reinterpret_cast<const s16x8*>(&W2s[d * 64 + sc]);
                accYt[db] = __builtin_amdgcn_mfma_f32_16x16x32_bf16(afrag, bfrag, accYt[db], 0, 0, 0);
            }
        }
        __syncthreads();      // all reads of W1s/W2s/Hs for chunk hc complete

        if (hc < 15) {
            STOREW();                         // write chunk hc+1
            if (hc < 14) { LOADW(hc + 2); }   // prefetch chunk hc+2
            __syncthreads();                  // new W tiles visible
        }
    }

    // epilogue: out[t][d] += w * (y + b2), fp32 atomics
    {
        const int tloc = tg * 16 + mrow;
        if (tloc < nvalid) {
            const float wt = wgts[tloc];
            float* obase = out + (size_t)toks[tloc] * D;
            #pragma unroll
            for (int db = 0; db < 8; ++db) {
                const int d0 = (dh * 8 + db) * 16 + kb * 4;
                #pragma unroll
                for (int r = 0; r < 4; ++r)
                    atomicAdd(obase + d0 + r, (accYt[db][r] + b2[e * D + d0 + r]) * wt);
            }
        }
    }
    #undef LOADW
    #undef STOREW
}

// ---------------- fallback expert FFN (round-5, fp32 weights, 256 thr) — used if ws too small ----------------
__global__ void __launch_bounds__(256) expert_kernel_fp32(
    const float* __restrict__ x, const float* __restrict__ w1, const float* __restrict__ w2,
    const float* __restrict__ b1, const float* __restrict__ b2,
    const int* __restrict__ cnt, const int* __restrict__ list, const float* __restrict__ wlist,
    float* __restrict__ out)
{
    const int e = blockIdx.y;
    int n = cnt[e]; n = (n < 0) ? 0 : ((n > NTOK) ? NTOK : n);
    const int tile0 = blockIdx.x * 64;
    if (tile0 >= n) return;
    const int nvalid = (n - tile0 < 64) ? (n - tile0) : 64;

    __shared__ __align__(16) unsigned short Xs [64 * 264];
    __shared__ __align__(16) unsigned short W1s[64 * 264];
    __shared__ __align__(16) unsigned short W2s[256 * 72];
    __shared__ __align__(16) unsigned short Hs [64 * 72];
    __shared__ int   toks[64];
    __shared__ float wgts[64];

    const int tid = threadIdx.x, lane = tid & 63, wv = tid >> 6;
    const int mrow = lane & 15, kb = lane >> 4;

    if (tid < 64) {
        if (tid < nvalid) {
            toks[tid] = list[e * NTOK + tile0 + tid] & 0x3FFF;
            wgts[tid] = wlist[e * NTOK + tile0 + tid];
        } else { toks[tid] = 0; wgts[tid] = 0.f; }
    }
    __syncthreads();

    #pragma unroll
    for (int r = 0; r < 8; ++r) {
        int v = r * 256 + tid, row = v >> 5, c8 = v & 31;
        s16x8 val = {0,0,0,0,0,0,0,0};
        if (row < nvalid) {
            const float* src = x + (size_t)toks[row] * D + c8 * 8;
            val = pack8(*reinterpret_cast<const float4*>(src),
                        *reinterpret_cast<const float4*>(src + 4));
        }
        *reinterpret_cast<s16x8*>(&Xs[row * 264 + c8 * 8]) = val;
    }

    f32x4 accYt[16];
    #pragma unroll
    for (int i = 0; i < 16; ++i) accYt[i] = (f32x4){0.f, 0.f, 0.f, 0.f};

    const int wr2 = wv >> 1, wc2 = wv & 1;
    const int hgrp = tid & 7, dblk = tid >> 3;
    const int dgrp = tid & 31, hblk8 = tid >> 5;

    for (int hc = 0; hc < 16; ++hc) {
        __syncthreads();
        {
            s16x8 Y8[8];
            #pragma unroll
            for (int i = 0; i < 8; ++i) {
                const float* src = w1 + ((size_t)(e * D + dblk * 8 + i)) * H + hc * 64 + hgrp * 8;
                Y8[i] = pack8(*reinterpret_cast<const float4*>(src),
                              *reinterpret_cast<const float4*>(src + 4));
            }
            #pragma unroll
            for (int j = 0; j < 8; ++j) {
                s16x8 V;
                #pragma unroll
                for (int i = 0; i < 8; ++i) V[i] = Y8[i][j];
                *reinterpret_cast<s16x8*>(&W1s[(hgrp * 8 + j) * 264 + dblk * 8]) = V;
            }
        }
        {
            s16x8 Z8[8];
            #pragma unroll
            for (int i = 0; i < 8; ++i) {
                const float* src = w2 + ((size_t)(e * H + hc * 64 + hblk8 * 8 + i)) * D + dgrp * 8;
                Z8[i] = pack8(*reinterpret_cast<const float4*>(src),
                              *reinterpret_cast<const float4*>(src + 4));
            }
            const int hswz = (hblk8 ^ (dgrp & 7)) << 3;
            #pragma unroll
            for (int j = 0; j < 8; ++j) {
                s16x8 V;
                #pragma unroll
                for (int i = 0; i < 8; ++i) V[i] = Z8[i][j];
                *reinterpret_cast<s16x8*>(&W2s[(dgrp * 8 + j) * 72 + hswz]) = V;
            }
        }
        __syncthreads();

        f32x4 accH[2][2];
        #pragma unroll
        for (int i = 0; i < 2; ++i)
            #pragma unroll
            for (int j = 0; j < 2; ++j) accH[i][j] = (f32x4){0.f, 0.f, 0.f, 0.f};
        #pragma unroll
        for (int ks = 0; ks < 8; ++ks) {
            const int koff = ks * 32 + kb * 8;
            s16x8 a0 = *reinterpret_cast<const s16x8*>(&Xs [((wr2*2+0)*16 + mrow)*264 + koff]);
            s16x8 a1 = *reinterpret_cast<const s16x8*>(&Xs [((wr2*2+1)*16 + mrow)*264 + koff]);
            s16x8 b0 = *reinterpret_cast<const s16x8*>(&W1s[((wc2*2+0)*16 + mrow)*264 + koff]);
            s16x8 b1v= *reinterpret_cast<const s16x8*>(&W1s[((wc2*2+1)*16 + mrow)*264 + koff]);
            accH[0][0] = __builtin_amdgcn_mfma_f32_16x16x32_bf16(a0, b0,  accH[0][0], 0, 0, 0);
            accH[0][1] = __builtin_amdgcn_mfma_f32_16x16x32_bf16(a0, b1v, accH[0][1], 0, 0, 0);
            accH[1][0] = __builtin_amdgcn_mfma_f32_16x16x32_bf16(a1, b0,  accH[1][0], 0, 0, 0);
            accH[1][1] = __builtin_amdgcn_mfma_f32_16x16x32_bf16(a1, b1v, accH[1][1], 0, 0, 0);
        }
        #pragma unroll
        for (int i = 0; i < 2; ++i)
            #pragma unroll
            for (int j = 0; j < 2; ++j) {
                const int hloc = (wc2*2 + j) * 16 + mrow;
                const float bias = b1[e * H + hc * 64 + hloc];
                #pragma unroll
                for (int r = 0; r < 4; ++r) {
                    const int m = (wr2*2 + i) * 16 + kb * 4 + r;
                    float vvf = accH[i][j][r] + bias;
                    float g = 0.5f * vvf * (1.0f + erff(vvf * 0.70710678118654752f));
                    Hs[m * 72 + hloc] = f2bf(g);
                }
            }
        __syncthreads();

        #pragma unroll
        for (int ks = 0; ks < 2; ++ks) {
            const int koff = ks * 32 + kb * 8;
            s16x8 bfrag = *reinterpret_cast<const s16x8*>(&Hs[(wv * 16 + mrow) * 72 + koff]);
            #pragma unroll
            for (int db = 0; db < 16; ++db) {
                const int arow = db * 16 + mrow;
                const int akey = (arow >> 3) & 7;
                s16x8 afrag = *reinterpret_cast<const s16x8*>(
                    &W2s[arow * 72 + (((ks * 4 + kb) ^ akey) << 3)]);
                accYt[db] = __builtin_amdgcn_mfma_f32_16x16x32_bf16(afrag, bfrag, accYt[db], 0, 0, 0);
            }
        }
    }

    {
        const int t = wv * 16 + mrow;
        if (t < nvalid) {
            const float wt = wgts[t];
            float* obase = out + (size_t)toks[t] * D;
            #pragma unroll
            for (int db = 0; db < 16; ++db) {
                const int d0 = db * 16 + kb * 4;
                #pragma unroll
                for (int r = 0; r < 4; ++r)
                    atomicAdd(obase + d0 + r, (accYt[db][r] + b2[e * D + d0 + r]) * wt);
            }
        }
    }
}

extern "C" void kernel_launch(void* const* d_in, const int* in_sizes, int n_in,
                              void* d_out, int out_size, void* d_ws, size_t ws_size,
                              hipStream_t stream)
{
    const float* x  = (const float*)d_in[0];
    const float* wr = (const float*)d_in[1];
    const float* br = (const float*)d_in[2];
    const float* w1 = (const float*)d_in[3];
    const float* b1 = (const float*)d_in[4];
    const float* w2 = (const float*)d_in[5];
    const float* b2 = (const float*)d_in[6];
    float* out = (float*)d_out;                 // [NTOK][D] fp32, then [NTOK][E] fp32 probs

    char* ws = (char*)d_ws;
    int*   cnt   = (int*)ws;                    //       256 B
    int*   list  = (int*)(ws + 256);            //   524,288 B  [E][NTOK]
    float* wlist = (float*)(ws + 524544);       //   524,288 B  [E][NTOK]
    unsigned short* w1t = (unsigned short*)(ws + 1048832);   // 4,194,304 B [E][H][D] bf16
    unsigned short* w2t = (unsigned short*)(ws + 5243136);   // 4,194,304 B [E][D][H] bf16
    const bool big = ws_size >= 9437440;        // deterministic across calls -> graph-safe

    hipMemsetAsync(out, 0, (size_t)NTOK * D * 4, stream);
    hipMemsetAsync(cnt, 0, 256, stream);
    if (big)
        convert_kernel<<<4096, 256, 0, stream>>>(w1, w2, w1t, w2t);
    router_kernel<<<NTOK / 16, 256, 0, stream>>>(x, wr, br, out + (size_t)NTOK * D, cnt, list, wlist);
    if (big)
        expert_kernel_v2<<<dim3(256, 8), 512, 0, stream>>>(x, w1t, w2t, b1, b2, cnt, list, wlist, out);
    else
        expert_kernel_fp32<<<dim3(256, 8), 256, 0, stream>>>(x, w1, w2, b1, b2, cnt, list, wlist, out);
}

// Round 7
// 302.386 us; speedup vs baseline: 1.7664x; 1.5376x over previous
//
#include <hip/hip_runtime.h>

typedef float f32x4 __attribute__((ext_vector_type(4)));
typedef short s16x8 __attribute__((ext_vector_type(8)));

static constexpr int NTOK = 16384;   // B*S
static constexpr int D    = 256;
static constexpr int H    = 1024;
static constexpr int E    = 8;

__device__ __forceinline__ unsigned short f2bf(float f) {
    unsigned int u = __float_as_uint(f);
    u += 0x7FFFu + ((u >> 16) & 1u);   // round-to-nearest-even
    return (unsigned short)(u >> 16);
}
__device__ __forceinline__ s16x8 pack8(float4 a, float4 b) {
    s16x8 v;
    v[0] = (short)f2bf(a.x); v[1] = (short)f2bf(a.y);
    v[2] = (short)f2bf(a.z); v[3] = (short)f2bf(a.w);
    v[4] = (short)f2bf(b.x); v[5] = (short)f2bf(b.y);
    v[6] = (short)f2bf(b.z); v[7] = (short)f2bf(b.w);
    return v;
}

// ---------------- one-time weight convert+transpose: fp32 -> bf16 ----------------
// w1 [E,D,H] -> w1t [E,H,D] bf16 ; w2 [E,H,D] -> w2t [E,D,H] bf16
__global__ void __launch_bounds__(256) convert_kernel(
    const float* __restrict__ w1, const float* __restrict__ w2,
    unsigned short* __restrict__ w1t, unsigned short* __restrict__ w2t)
{
    __shared__ unsigned short tile[32][33];
    int b = blockIdx.x;
    const float* src; unsigned short* dst;
    int Rr, Cc, tr, tc;
    if (b < 2048) {                      // w1: [256][1024] per expert
        int e = b >> 8, tt = b & 255;
        Rr = 256; Cc = 1024; tr = tt >> 5; tc = tt & 31;
        src = w1 + (size_t)e * Rr * Cc; dst = w1t + (size_t)e * Rr * Cc;
    } else {                             // w2: [1024][256] per expert
        b -= 2048;
        int e = b >> 8, tt = b & 255;
        Rr = 1024; Cc = 256; tr = tt >> 3; tc = tt & 7;
        src = w2 + (size_t)e * Rr * Cc; dst = w2t + (size_t)e * Rr * Cc;
    }
    const int tid = threadIdx.x;
    const int c = tid & 31, r0 = tid >> 5;
    #pragma unroll
    for (int rr = 0; rr < 32; rr += 8)
        tile[r0 + rr][c] = f2bf(src[(size_t)(tr * 32 + r0 + rr) * Cc + tc * 32 + c]);
    __syncthreads();
    #pragma unroll
    for (int rr = 0; rr < 32; rr += 8)
        dst[(size_t)(tc * 32 + r0 + rr) * Rr + tr * 32 + c] = tile[c][r0 + rr];
}

// ---------------- router: 1 thr/token, block-aggregated expert counters ----------------
__global__ void __launch_bounds__(256) router_kernel(
    const float* __restrict__ x,          // [NTOK][D] fp32
    const float* __restrict__ wr,         // [D][E]    fp32
    const float* __restrict__ br,         // [E]       fp32
    float* __restrict__ probs_out,        // [NTOK][E] fp32
    int* __restrict__ cnt, int* __restrict__ list, float* __restrict__ wlist)
{
    __shared__ float wrs[D][E];
    __shared__ int lcnt[8];
    __shared__ int gbase[8];
    const int tid = threadIdx.x;
    {
        float4 a = *reinterpret_cast<const float4*>(wr + tid * 8);
        float4 b = *reinterpret_cast<const float4*>(wr + tid * 8 + 4);
        wrs[tid][0] = a.x; wrs[tid][1] = a.y; wrs[tid][2] = a.z; wrs[tid][3] = a.w;
        wrs[tid][4] = b.x; wrs[tid][5] = b.y; wrs[tid][6] = b.z; wrs[tid][7] = b.w;
    }
    if (tid < 8) lcnt[tid] = 0;
    __syncthreads();

    const int t = blockIdx.x * 256 + tid;
    float lg[8];
    #pragma unroll
    for (int e = 0; e < 8; ++e) lg[e] = br[e];

    const float* xr = x + (size_t)t * D;
    for (int d0 = 0; d0 < D; d0 += 4) {
        float4 xv = *reinterpret_cast<const float4*>(xr + d0);
        #pragma unroll
        for (int j = 0; j < 4; ++j) {
            const float xf = (j == 0) ? xv.x : (j == 1) ? xv.y : (j == 2) ? xv.z : xv.w;
            #pragma unroll
            for (int e = 0; e < 8; ++e) lg[e] += xf * wrs[d0 + j][e];
        }
    }
    float mx = lg[0];
    #pragma unroll
    for (int e = 1; e < 8; ++e) mx = fmaxf(mx, lg[e]);
    float p[8], s = 0.f;
    #pragma unroll
    for (int e = 0; e < 8; ++e) { p[e] = expf(lg[e] - mx); s += p[e]; }
    const float inv = 1.f / s;
    #pragma unroll
    for (int e = 0; e < 8; ++e) p[e] *= inv;
    float4 o0 = {p[0], p[1], p[2], p[3]}, o1 = {p[4], p[5], p[6], p[7]};
    *reinterpret_cast<float4*>(probs_out + t * 8)     = o0;
    *reinterpret_cast<float4*>(probs_out + t * 8 + 4) = o1;

    int i1 = 0;
    #pragma unroll
    for (int e = 1; e < 8; ++e) if (p[e] > p[i1]) i1 = e;       // strict > : lowest index wins
    int i2 = (i1 == 0) ? 1 : 0;
    #pragma unroll
    for (int e = 0; e < 8; ++e) if (e != i1 && p[e] > p[i2]) i2 = e;

    const float sw = p[i1] + p[i2];
    const float wa = p[i1] / sw, wb = p[i2] / sw;
    const int lp1 = atomicAdd(&lcnt[i1], 1);     // LDS atomics: cheap
    const int lp2 = atomicAdd(&lcnt[i2], 1);
    __syncthreads();
    if (tid < 8) gbase[tid] = atomicAdd(&cnt[tid], lcnt[tid]);   // 8 global atomics/block
    __syncthreads();
    int pos = gbase[i1] + lp1;
    list[i1 * NTOK + pos] = t; wlist[i1 * NTOK + pos] = wa;
    pos = gbase[i2] + lp2;
    list[i2 * NTOK + pos] = t; wlist[i2 * NTOK + pos] = wb;
}

// ---------------- expert FFN v3: 512 thr, 32-h chunks, 68.5 KB LDS -> 2 blocks/CU ----------------
__global__ void __launch_bounds__(512, 4) expert_kernel_v3(
    const float* __restrict__ x,              // [NTOK][D] fp32
    const unsigned short* __restrict__ w1t,   // [E][H][D] bf16
    const unsigned short* __restrict__ w2t,   // [E][D][H] bf16
    const float* __restrict__ b1,             // [E][H]
    const float* __restrict__ b2,             // [E][D]
    const int* __restrict__ cnt, const int* __restrict__ list,
    const float* __restrict__ wlist,
    float* __restrict__ out)                  // [NTOK][D] fp32 (zeroed)
{
    const int e = blockIdx.y;
    int n = cnt[e]; n = (n < 0) ? 0 : ((n > NTOK) ? NTOK : n);
    const int tile0 = blockIdx.x * 64;
    if (tile0 >= n) return;
    const int nvalid = (n - tile0 < 64) ? (n - tile0) : 64;

    __shared__ __align__(16) unsigned short Xs [64 * 256];  // [tok][d]   swizzled (8 col-grps key row&7)
    __shared__ __align__(16) unsigned short W1s[32 * 256];  // [h][d]     swizzled (8 col-grps key h&7)
    __shared__ __align__(16) unsigned short W2s[256 * 32];  // [d][h]     swizzled (4 col-grps key (d&3)^((d>>2)&3))
    __shared__ __align__(16) unsigned short Hs [64 * 32];   // [tok][h]   swizzled (4 col-grps key (t&3)^((t>>2)&3))
    __shared__ int   toks[64];
    __shared__ float wgts[64];

    const int tid  = threadIdx.x;
    const int lane = tid & 63;
    const int wv   = tid >> 6;          // 0..7
    const int mrow = lane & 15;
    const int kb   = lane >> 4;         // 0..3
    const int key8 = mrow & 7;                          // Xs/W1s read key
    const int key4 = (mrow & 3) ^ ((mrow >> 2) & 3);    // W2s/Hs read key
    const int rb   = wv & 3;            // stage1 token block / stage2 token group
    const int chb  = wv >> 2;           // stage1 h half (0..1) / stage2 d half

    if (tid < 64) {
        if (tid < nvalid) {
            toks[tid] = list[e * NTOK + tile0 + tid] & 0x3FFF;
            wgts[tid] = wlist[e * NTOK + tile0 + tid];
        } else { toks[tid] = 0; wgts[tid] = 0.f; }
    }
    __syncthreads();

    // gather X rows into LDS as bf16, swizzled (invalid rows -> zeros)
    #pragma unroll
    for (int k = 0; k < 4; ++k) {
        const int s = k * 512 + tid;
        const int row = s >> 5, c = s & 31;
        s16x8 val = {0,0,0,0,0,0,0,0};
        if (row < nvalid) {
            const float* src = x + (size_t)toks[row] * D + c * 8;
            val = pack8(*reinterpret_cast<const float4*>(src),
                        *reinterpret_cast<const float4*>(src + 4));
        }
        *reinterpret_cast<s16x8*>(&Xs[row * 256 + ((c ^ (row & 7)) << 3)]) = val;
    }

    // weight prefetch registers (2 chunks ahead)
    s16x8 pfW1[2], pfW2[2];
    const size_t w1b = (size_t)e * H * D;
    const size_t w2b = (size_t)e * D * H;

    #define LOADW(HC)                                                                   \
        _Pragma("unroll")                                                               \
        for (int k = 0; k < 2; ++k) {                                                   \
            const int s1 = k * 512 + tid, h1 = s1 >> 5, c1 = s1 & 31;                   \
            pfW1[k] = *reinterpret_cast<const s16x8*>(                                  \
                w1t + w1b + (size_t)((HC) * 32 + h1) * D + c1 * 8);                     \
            const int s2 = k * 512 + tid, d2 = s2 >> 2, c2 = s2 & 3;                    \
            pfW2[k] = *reinterpret_cast<const s16x8*>(                                  \
                w2t + w2b + (size_t)d2 * H + (HC) * 32 + c2 * 8);                       \
        }
    #define STOREW()                                                                    \
        _Pragma("unroll")                                                               \
        for (int k = 0; k < 2; ++k) {                                                   \
            const int s1 = k * 512 + tid, h1 = s1 >> 5, c1 = s1 & 31;                   \
            *reinterpret_cast<s16x8*>(&W1s[h1 * 256 + ((c1 ^ (h1 & 7)) << 3)]) = pfW1[k]; \
            const int s2 = k * 512 + tid, d2 = s2 >> 2, c2 = s2 & 3;                    \
            const int k2 = (d2 & 3) ^ ((d2 >> 2) & 3);                                  \
            *reinterpret_cast<s16x8*>(&W2s[d2 * 32 + ((c2 ^ k2) << 3)]) = pfW2[k];      \
        }

    LOADW(0);
    __syncthreads();          // Xs/toks visible (W not yet read by anyone)
    STOREW();
    LOADW(1);

    f32x4 accYt[8];           // stage2: d = (chb*8+db)*16 + kb*4 + r, t = rb*16 + mrow
    #pragma unroll
    for (int i = 0; i < 8; ++i) accYt[i] = (f32x4){0.f, 0.f, 0.f, 0.f};

    __syncthreads();          // W chunk0 visible

    for (int hc = 0; hc < 32; ++hc) {
        // ---- stage 1: one 16x16 tile per wave: Ht[rb][chb] = X(rb) @ W1chunk(chb) ----
        f32x4 accH = (f32x4){0.f, 0.f, 0.f, 0.f};
        const int arow = rb * 16 + mrow;      // token
        const int brow = chb * 16 + mrow;     // h within chunk
        #pragma unroll
        for (int ks = 0; ks < 8; ++ks) {
            const int sc = ((ks * 4 + kb) ^ key8) << 3;
            s16x8 a = *reinterpret_cast<const s16x8*>(&Xs [arow * 256 + sc]);
            s16x8 b = *reinterpret_cast<const s16x8*>(&W1s[brow * 256 + sc]);
            accH = __builtin_amdgcn_mfma_f32_16x16x32_bf16(a, b, accH, 0, 0, 0);
        }
        // gelu -> Hs (lane: h col = brow, tokens = rb*16 + kb*4 + r)
        {
            const float bias = b1[e * H + hc * 32 + brow];
            const int cg = brow >> 3, hlo = brow & 7;
            #pragma unroll
            for (int r = 0; r < 4; ++r) {
                const int t = rb * 16 + kb * 4 + r;
                const int kt = (t & 3) ^ ((t >> 2) & 3);
                const float vvf = accH[r] + bias;
                const float g = 0.5f * vvf * (1.0f + erff(vvf * 0.70710678118654752f));
                Hs[t * 32 + ((cg ^ kt) << 3) + hlo] = f2bf(g);
            }
        }
        __syncthreads();      // Hs visible

        // ---- stage 2: accYt += W2chunk(d-tiles) @ H^T, K=32 (single MFMA step) ----
        {
            const int trow = rb * 16 + mrow;
            s16x8 bfrag = *reinterpret_cast<const s16x8*>(&Hs[trow * 32 + ((kb ^ key4) << 3)]);
            #pragma unroll
            for (int db = 0; db < 8; ++db) {
                const int d = (chb * 8 + db) * 16 + mrow;
                s16x8 afrag = *reinterpret_cast<const s16x8*>(&W2s[d * 32 + ((kb ^ key4) << 3)]);
                accYt[db] = __builtin_amdgcn_mfma_f32_16x16x32_bf16(afrag, bfrag, accYt[db], 0, 0, 0);
            }
        }
        __syncthreads();      // all reads of W1s/W2s/Hs for chunk hc complete

        if (hc < 31) {
            STOREW();                          // write chunk hc+1
            if (hc < 30) { LOADW(hc + 2); }    // prefetch chunk hc+2
            __syncthreads();                   // new W tiles visible
        }
    }

    // epilogue: out[t][d] += w * (y + b2), fp32 atomics
    {
        const int tloc = rb * 16 + mrow;
        if (tloc < nvalid) {
            const float wt = wgts[tloc];
            float* obase = out + (size_t)toks[tloc] * D;
            #pragma unroll
            for (int db = 0; db < 8; ++db) {
                const int d0 = (chb * 8 + db) * 16 + kb * 4;
                const float4 bv = *reinterpret_cast<const float4*>(b2 + e * D + d0);
                atomicAdd(obase + d0 + 0, (accYt[db][0] + bv.x) * wt);
                atomicAdd(obase + d0 + 1, (accYt[db][1] + bv.y) * wt);
                atomicAdd(obase + d0 + 2, (accYt[db][2] + bv.z) * wt);
                atomicAdd(obase + d0 + 3, (accYt[db][3] + bv.w) * wt);
            }
        }
    }
    #undef LOADW
    #undef STOREW
}

// ---------------- fallback expert FFN (round-5, fp32 weights, 256 thr) — used if ws too small ----------------
__global__ void __launch_bounds__(256) expert_kernel_fp32(
    const float* __restrict__ x, const float* __restrict__ w1, const float* __restrict__ w2,
    const float* __restrict__ b1, const float* __restrict__ b2,
    const int* __restrict__ cnt, const int* __restrict__ list, const float* __restrict__ wlist,
    float* __restrict__ out)
{
    const int e = blockIdx.y;
    int n = cnt[e]; n = (n < 0) ? 0 : ((n > NTOK) ? NTOK : n);
    const int tile0 = blockIdx.x * 64;
    if (tile0 >= n) return;
    const int nvalid = (n - tile0 < 64) ? (n - tile0) : 64;

    __shared__ __align__(16) unsigned short Xs [64 * 264];
    __shared__ __align__(16) unsigned short W1s[64 * 264];
    __shared__ __align__(16) unsigned short W2s[256 * 72];
    __shared__ __align__(16) unsigned short Hs [64 * 72];
    __shared__ int   toks[64];
    __shared__ float wgts[64];

    const int tid = threadIdx.x, lane = tid & 63, wv = tid >> 6;
    const int mrow = lane & 15, kb = lane >> 4;

    if (tid < 64) {
        if (tid < nvalid) {
            toks[tid] = list[e * NTOK + tile0 + tid] & 0x3FFF;
            wgts[tid] = wlist[e * NTOK + tile0 + tid];
        } else { toks[tid] = 0; wgts[tid] = 0.f; }
    }
    __syncthreads();

    #pragma unroll
    for (int r = 0; r < 8; ++r) {
        int v = r * 256 + tid, row = v >> 5, c8 = v & 31;
        s16x8 val = {0,0,0,0,0,0,0,0};
        if (row < nvalid) {
            const float* src = x + (size_t)toks[row] * D + c8 * 8;
            val = pack8(*reinterpret_cast<const float4*>(src),
                        *reinterpret_cast<const float4*>(src + 4));
        }
        *reinterpret_cast<s16x8*>(&Xs[row * 264 + c8 * 8]) = val;
    }

    f32x4 accYt[16];
    #pragma unroll
    for (int i = 0; i < 16; ++i) accYt[i] = (f32x4){0.f, 0.f, 0.f, 0.f};

    const int wr2 = wv >> 1, wc2 = wv & 1;
    const int hgrp = tid & 7, dblk = tid >> 3;
    const int dgrp = tid & 31, hblk8 = tid >> 5;

    for (int hc = 0; hc < 16; ++hc) {
        __syncthreads();
        {
            s16x8 Y8[8];
            #pragma unroll
            for (int i = 0; i < 8; ++i) {
                const float* src = w1 + ((size_t)(e * D + dblk * 8 + i)) * H + hc * 64 + hgrp * 8;
                Y8[i] = pack8(*reinterpret_cast<const float4*>(src),
                              *reinterpret_cast<const float4*>(src + 4));
            }
            #pragma unroll
            for (int j = 0; j < 8; ++j) {
                s16x8 V;
                #pragma unroll
                for (int i = 0; i < 8; ++i) V[i] = Y8[i][j];
                *reinterpret_cast<s16x8*>(&W1s[(hgrp * 8 + j) * 264 + dblk * 8]) = V;
            }
        }
        {
            s16x8 Z8[8];
            #pragma unroll
            for (int i = 0; i < 8; ++i) {
                const float* src = w2 + ((size_t)(e * H + hc * 64 + hblk8 * 8 + i)) * D + dgrp * 8;
                Z8[i] = pack8(*reinterpret_cast<const float4*>(src),
                              *reinterpret_cast<const float4*>(src + 4));
            }
            const int hswz = (hblk8 ^ (dgrp & 7)) << 3;
            #pragma unroll
            for (int j = 0; j < 8; ++j) {
                s16x8 V;
                #pragma unroll
                for (int i = 0; i < 8; ++i) V[i] = Z8[i][j];
                *reinterpret_cast<s16x8*>(&W2s[(dgrp * 8 + j) * 72 + hswz]) = V;
            }
        }
        __syncthreads();

        f32x4 accH[2][2];
        #pragma unroll
        for (int i = 0; i < 2; ++i)
            #pragma unroll
            for (int j = 0; j < 2; ++j) accH[i][j] = (f32x4){0.f, 0.f, 0.f, 0.f};
        #pragma unroll
        for (int ks = 0; ks < 8; ++ks) {
            const int koff = ks * 32 + kb * 8;
            s16x8 a0 = *reinterpret_cast<const s16x8*>(&Xs [((wr2*2+0)*16 + mrow)*264 + koff]);
            s16x8 a1 = *reinterpret_cast<const s16x8*>(&Xs [((wr2*2+1)*16 + mrow)*264 + koff]);
            s16x8 b0 = *reinterpret_cast<const s16x8*>(&W1s[((wc2*2+0)*16 + mrow)*264 + koff]);
            s16x8 b1v= *reinterpret_cast<const s16x8*>(&W1s[((wc2*2+1)*16 + mrow)*264 + koff]);
            accH[0][0] = __builtin_amdgcn_mfma_f32_16x16x32_bf16(a0, b0,  accH[0][0], 0, 0, 0);
            accH[0][1] = __builtin_amdgcn_mfma_f32_16x16x32_bf16(a0, b1v, accH[0][1], 0, 0, 0);
            accH[1][0] = __builtin_amdgcn_mfma_f32_16x16x32_bf16(a1, b0,  accH[1][0], 0, 0, 0);
            accH[1][1] = __builtin_amdgcn_mfma_f32_16x16x32_bf16(a1, b1v, accH[1][1], 0, 0, 0);
        }
        #pragma unroll
        for (int i = 0; i < 2; ++i)
            #pragma unroll
            for (int j = 0; j < 2; ++j) {
                const int hloc = (wc2*2 + j) * 16 + mrow;
                const float bias = b1[e * H + hc * 64 + hloc];
                #pragma unroll
                for (int r = 0; r < 4; ++r) {
                    const int m = (wr2*2 + i) * 16 + kb * 4 + r;
                    float vvf = accH[i][j][r] + bias;
                    float g = 0.5f * vvf * (1.0f + erff(vvf * 0.70710678118654752f));
                    Hs[m * 72 + hloc] = f2bf(g);
                }
            }
        __syncthreads();

        #pragma unroll
        for (int ks = 0; ks < 2; ++ks) {
            const int koff = ks * 32 + kb * 8;
            s16x8 bfrag = *reinterpret_cast<const s16x8*>(&Hs[(wv * 16 + mrow) * 72 + koff]);
            #pragma unroll
            for (int db = 0; db < 16; ++db) {
                const int arow = db * 16 + mrow;
                const int akey = (arow >> 3) & 7;
                s16x8 afrag = *reinterpret_cast<const s16x8*>(
                    &W2s[arow * 72 + (((ks * 4 + kb) ^ akey) << 3)]);
                accYt[db] = __builtin_amdgcn_mfma_f32_16x16x32_bf16(afrag, bfrag, accYt[db], 0, 0, 0);
            }
        }
    }

    {
        const int t = wv * 16 + mrow;
        if (t < nvalid) {
            const float wt = wgts[t];
            float* obase = out + (size_t)toks[t] * D;
            #pragma unroll
            for (int db = 0; db < 16; ++db) {
                const int d0 = db * 16 + kb * 4;
                #pragma unroll
                for (int r = 0; r < 4; ++r)
                    atomicAdd(obase + d0 + r, (accYt[db][r] + b2[e * D + d0 + r]) * wt);
            }
        }
    }
}

extern "C" void kernel_launch(void* const* d_in, const int* in_sizes, int n_in,
                              void* d_out, int out_size, void* d_ws, size_t ws_size,
                              hipStream_t stream)
{
    const float* x  = (const float*)d_in[0];
    const float* wr = (const float*)d_in[1];
    const float* br = (const float*)d_in[2];
    const float* w1 = (const float*)d_in[3];
    const float* b1 = (const float*)d_in[4];
    const float* w2 = (const float*)d_in[5];
    const float* b2 = (const float*)d_in[6];
    float* out = (float*)d_out;                 // [NTOK][D] fp32, then [NTOK][E] fp32 probs

    char* ws = (char*)d_ws;
    int*   cnt   = (int*)ws;                    //       256 B
    int*   list  = (int*)(ws + 256);            //   524,288 B  [E][NTOK]
    float* wlist = (float*)(ws + 524544);       //   524,288 B  [E][NTOK]
    unsigned short* w1t = (unsigned short*)(ws + 1048832);   // 4,194,304 B [E][H][D] bf16
    unsigned short* w2t = (unsigned short*)(ws + 5243136);   // 4,194,304 B [E][D][H] bf16
    const bool big = ws_size >= 9437440;        // deterministic across calls -> graph-safe

    hipMemsetAsync(out, 0, (size_t)NTOK * D * 4, stream);
    hipMemsetAsync(cnt, 0, 256, stream);
    if (big)
        convert_kernel<<<4096, 256, 0, stream>>>(w1, w2, w1t, w2t);
    router_kernel<<<NTOK / 256, 256, 0, stream>>>(x, wr, br, out + (size_t)NTOK * D, cnt, list, wlist);
    if (big)
        expert_kernel_v3<<<dim3(256, 8), 512, 0, stream>>>(x, w1t, w2t, b1, b2, cnt, list, wlist, out);
    else
        expert_kernel_fp32<<<dim3(256, 8), 256, 0, stream>>>(x, w1, w2, b1, b2, cnt, list, wlist, out);
}

// Round 8
// 282.119 us; speedup vs baseline: 1.8933x; 1.0718x over previous
//
#include <hip/hip_runtime.h>

typedef float f32x4 __attribute__((ext_vector_type(4)));
typedef short s16x8 __attribute__((ext_vector_type(8)));

static constexpr int NTOK = 16384;   // B*S
static constexpr int D    = 256;
static constexpr int H    = 1024;
static constexpr int E    = 8;

__device__ __forceinline__ unsigned short f2bf(float f) {
    unsigned int u = __float_as_uint(f);
    u += 0x7FFFu + ((u >> 16) & 1u);   // round-to-nearest-even
    return (unsigned short)(u >> 16);
}
__device__ __forceinline__ s16x8 pack8(float4 a, float4 b) {
    s16x8 v;
    v[0] = (short)f2bf(a.x); v[1] = (short)f2bf(a.y);
    v[2] = (short)f2bf(a.z); v[3] = (short)f2bf(a.w);
    v[4] = (short)f2bf(b.x); v[5] = (short)f2bf(b.y);
    v[6] = (short)f2bf(b.z); v[7] = (short)f2bf(b.w);
    return v;
}

// ---------------- one-time weight convert+transpose: fp32 -> bf16 ----------------
// w1 [E,D,H] -> w1t [E,H,D] bf16 ; w2 [E,H,D] -> w2t [E,D,H] bf16
__global__ void __launch_bounds__(256) convert_kernel(
    const float* __restrict__ w1, const float* __restrict__ w2,
    unsigned short* __restrict__ w1t, unsigned short* __restrict__ w2t)
{
    __shared__ unsigned short tile[32][33];
    int b = blockIdx.x;
    const float* src; unsigned short* dst;
    int Rr, Cc, tr, tc;
    if (b < 2048) {                      // w1: [256][1024] per expert
        int e = b >> 8, tt = b & 255;
        Rr = 256; Cc = 1024; tr = tt >> 5; tc = tt & 31;
        src = w1 + (size_t)e * Rr * Cc; dst = w1t + (size_t)e * Rr * Cc;
    } else {                             // w2: [1024][256] per expert
        b -= 2048;
        int e = b >> 8, tt = b & 255;
        Rr = 1024; Cc = 256; tr = tt >> 3; tc = tt & 7;
        src = w2 + (size_t)e * Rr * Cc; dst = w2t + (size_t)e * Rr * Cc;
    }
    const int tid = threadIdx.x;
    const int c = tid & 31, r0 = tid >> 5;
    #pragma unroll
    for (int rr = 0; rr < 32; rr += 8)
        tile[r0 + rr][c] = f2bf(src[(size_t)(tr * 32 + r0 + rr) * Cc + tc * 32 + c]);
    __syncthreads();
    #pragma unroll
    for (int rr = 0; rr < 32; rr += 8)
        dst[(size_t)(tc * 32 + r0 + rr) * Rr + tr * 32 + c] = tile[c][r0 + rr];
}

// ---------------- router: 16 lanes/token (coalesced), block-aggregated atomics ----------------
__global__ void __launch_bounds__(1024) router_kernel(
    const float* __restrict__ x,          // [NTOK][D] fp32
    const float* __restrict__ wr,         // [D][E]    fp32
    const float* __restrict__ br,         // [E]       fp32
    float* __restrict__ probs_out,        // [NTOK][E] fp32
    int* __restrict__ cnt, int* __restrict__ list, float* __restrict__ wlist)
{
    __shared__ float wrs[D][9];           // +1 pad: breaks same-bank row stride
    __shared__ int lcnt[8];
    __shared__ int gbase[8];
    const int tid = threadIdx.x;
    if (tid < 256) {
        float4 a = *reinterpret_cast<const float4*>(wr + tid * 8);
        float4 b = *reinterpret_cast<const float4*>(wr + tid * 8 + 4);
        wrs[tid][0] = a.x; wrs[tid][1] = a.y; wrs[tid][2] = a.z; wrs[tid][3] = a.w;
        wrs[tid][4] = b.x; wrs[tid][5] = b.y; wrs[tid][6] = b.z; wrs[tid][7] = b.w;
    }
    if (tid < 8) lcnt[tid] = 0;
    __syncthreads();

    const int g = tid >> 4, l = tid & 15;            // 64 tokens/block, 16 lanes/token
    const int t = blockIdx.x * 64 + g;

    float lg[8];
    #pragma unroll
    for (int e = 0; e < 8; ++e) lg[e] = 0.f;

    const float* xr = x + (size_t)t * D;
    #pragma unroll
    for (int r = 0; r < 4; ++r) {
        const int d = r * 64 + l * 4;
        float4 xv = *reinterpret_cast<const float4*>(xr + d);
        #pragma unroll
        for (int j = 0; j < 4; ++j) {
            const float xf = (j == 0) ? xv.x : (j == 1) ? xv.y : (j == 2) ? xv.z : xv.w;
            #pragma unroll
            for (int e = 0; e < 8; ++e) lg[e] += xf * wrs[d + j][e];
        }
    }
    #pragma unroll
    for (int off = 1; off < 16; off <<= 1)
        #pragma unroll
        for (int e = 0; e < 8; ++e) lg[e] += __shfl_xor(lg[e], off, 16);

    int i1 = 0, i2 = 0, lp1 = 0, lp2 = 0;
    float wa = 0.f, wb = 0.f;
    if (l == 0) {
        #pragma unroll
        for (int e = 0; e < 8; ++e) lg[e] += br[e];
        float mx = lg[0];
        #pragma unroll
        for (int e = 1; e < 8; ++e) mx = fmaxf(mx, lg[e]);
        float p[8], s = 0.f;
        #pragma unroll
        for (int e = 0; e < 8; ++e) { p[e] = expf(lg[e] - mx); s += p[e]; }
        const float inv = 1.f / s;
        #pragma unroll
        for (int e = 0; e < 8; ++e) p[e] *= inv;
        float4 o0 = {p[0], p[1], p[2], p[3]}, o1 = {p[4], p[5], p[6], p[7]};
        *reinterpret_cast<float4*>(probs_out + t * 8)     = o0;
        *reinterpret_cast<float4*>(probs_out + t * 8 + 4) = o1;

        #pragma unroll
        for (int e = 1; e < 8; ++e) if (p[e] > p[i1]) i1 = e;   // strict > : lowest index wins
        i2 = (i1 == 0) ? 1 : 0;
        #pragma unroll
        for (int e = 0; e < 8; ++e) if (e != i1 && p[e] > p[i2]) i2 = e;
        const float sw = p[i1] + p[i2];
        wa = p[i1] / sw; wb = p[i2] / sw;
        lp1 = atomicAdd(&lcnt[i1], 1);
        lp2 = atomicAdd(&lcnt[i2], 1);
    }
    __syncthreads();
    if (tid < 8) gbase[tid] = atomicAdd(&cnt[tid], lcnt[tid]);   // 8 global atomics/block
    __syncthreads();
    if (l == 0) {
        int pos = gbase[i1] + lp1;
        list[i1 * NTOK + pos] = t; wlist[i1 * NTOK + pos] = wa;
        pos = gbase[i2] + lp2;
        list[i2 * NTOK + pos] = t; wlist[i2 * NTOK + pos] = wb;
    }
}

// ---------------- expert FFN v4: register A-frags, full dbuf, 1 barrier/chunk ----------------
__global__ void __launch_bounds__(512, 4) expert_kernel_v4(
    const float* __restrict__ x,              // [NTOK][D] fp32
    const unsigned short* __restrict__ w1t,   // [E][H][D] bf16
    const unsigned short* __restrict__ w2t,   // [E][D][H] bf16
    const float* __restrict__ b1,             // [E][H]
    const float* __restrict__ b2,             // [E][D]
    const int* __restrict__ cnt, const int* __restrict__ list,
    const float* __restrict__ wlist,
    float* __restrict__ out)                  // [NTOK][D] fp32 (zeroed)
{
    const int e = blockIdx.y;
    int n = cnt[e]; n = (n < 0) ? 0 : ((n > NTOK) ? NTOK : n);
    const int tile0 = blockIdx.x * 64;
    if (tile0 >= n) return;
    const int nvalid = (n - tile0 < 64) ? (n - tile0) : 64;

    // double-buffered tiles; all hot access patterns verified <=2-way bank aliasing
    __shared__ __align__(16) unsigned short W1s[2][32 * 264];  // [h][d+8]  pad
    __shared__ __align__(16) unsigned short W2s[2][256 * 32];  // [d][h]    XOR-swizzled
    __shared__ __align__(16) unsigned short Hs [2][64 * 40];   // [t][h+8]  pad
    __shared__ int   toks[64];
    __shared__ float wgts[64];

    const int tid  = threadIdx.x;
    const int lane = tid & 63;
    const int wv   = tid >> 6;          // 0..7
    const int mrow = lane & 15;
    const int kb   = lane >> 4;         // 0..3
    const int key4 = (mrow & 3) ^ ((mrow >> 2) & 3);   // W2s read swizzle key
    const int rb    = wv & 3;           // stage1 token block
    const int chb   = wv >> 2;          // stage1 h half
    const int tpart = wv & 1;           // stage2 token half (2 groups of 16)
    const int dpart = wv >> 1;          // stage2 d quarter (4 blocks of 16)

    if (tid < 64) {
        if (tid < nvalid) {
            toks[tid] = list[e * NTOK + tile0 + tid] & 0x3FFF;
            wgts[tid] = wlist[e * NTOK + tile0 + tid];
        } else { toks[tid] = 0; wgts[tid] = 0.f; }
    }

    const size_t w1b = (size_t)e * H * D;
    const size_t w2b = (size_t)e * D * H;
    s16x8 pfW1[2], pfW2[2];

    #define LOADW1(HC)                                                                  \
        _Pragma("unroll")                                                               \
        for (int k = 0; k < 2; ++k) {                                                   \
            const int s = k * 512 + tid, h1 = s >> 5, c1 = s & 31;                      \
            pfW1[k] = *reinterpret_cast<const s16x8*>(                                  \
                w1t + w1b + (size_t)((HC) * 32 + h1) * D + c1 * 8);                     \
        }
    #define STOREW1(BUF)                                                                \
        _Pragma("unroll")                                                               \
        for (int k = 0; k < 2; ++k) {                                                   \
            const int s = k * 512 + tid, h1 = s >> 5, c1 = s & 31;                      \
            *reinterpret_cast<s16x8*>(&W1s[BUF][h1 * 264 + c1 * 8]) = pfW1[k];          \
        }
    #define LOADW2(HC)                                                                  \
        _Pragma("unroll")                                                               \
        for (int k = 0; k < 2; ++k) {                                                   \
            const int s = k * 512 + tid, d2 = s >> 2, c2 = s & 3;                       \
            pfW2[k] = *reinterpret_cast<const s16x8*>(                                  \
                w2t + w2b + (size_t)d2 * H + (HC) * 32 + c2 * 8);                       \
        }
    #define STOREW2(BUF)                                                                \
        _Pragma("unroll")                                                               \
        for (int k = 0; k < 2; ++k) {                                                   \
            const int s = k * 512 + tid, d2 = s >> 2, c2 = s & 3;                       \
            const int k2 = (d2 & 3) ^ ((d2 >> 2) & 3);                                  \
            *reinterpret_cast<s16x8*>(&W2s[BUF][d2 * 32 + ((c2 ^ k2) << 3)]) = pfW2[k]; \
        }

    LOADW1(0);                 // chunk 0 -> pf (no toks dependency)
    __syncthreads();           // toks visible

    // A-fragments in registers: token row rb*16+mrow, full K=256
    s16x8 aFrag[8];
    {
        const float* xrow = x + (size_t)toks[rb * 16 + mrow] * D;
        #pragma unroll
        for (int ks = 0; ks < 8; ++ks) {
            const float* src = xrow + ks * 32 + kb * 8;
            aFrag[ks] = pack8(*reinterpret_cast<const float4*>(src),
                              *reinterpret_cast<const float4*>(src + 4));
        }
    }

    STOREW1(0);                // chunk 0 into W1s[0]
    LOADW1(1);                 // chunk 1 -> pfW1
    LOADW2(0);                 // chunk 0 -> pfW2
    __syncthreads();           // W1s[0] visible

    f32x4 accYt[2][4];         // [tg][db]: t=(tpart*2+tg)*16+mrow, d=(dpart*4+db)*16+kb*4+r
    #pragma unroll
    for (int i = 0; i < 2; ++i)
        #pragma unroll
        for (int j = 0; j < 4; ++j) accYt[i][j] = (f32x4){0.f, 0.f, 0.f, 0.f};

    for (int hc = 0; hc < 32; ++hc) {
        const int cur = hc & 1, nxt = cur ^ 1;

        // staging for future chunks (disjoint buffers from this iteration's reads)
        if (hc < 31) { STOREW1(nxt); }           // chunk hc+1
        if (hc < 30) { LOADW1(hc + 2); }
        STOREW2(cur);                            // chunk hc (read next iteration)
        if (hc < 31) { LOADW2(hc + 1); }

        // ---- stage 1 (chunk hc): H = gelu(X @ W1 + b1) -> Hs[cur] ----
        f32x4 accH = (f32x4){0.f, 0.f, 0.f, 0.f};
        {
            const int brow = chb * 16 + mrow;
            #pragma unroll
            for (int ks = 0; ks < 8; ++ks) {
                s16x8 bfrag = *reinterpret_cast<const s16x8*>(
                    &W1s[cur][brow * 264 + ks * 32 + kb * 8]);
                accH = __builtin_amdgcn_mfma_f32_16x16x32_bf16(aFrag[ks], bfrag, accH, 0, 0, 0);
            }
            const float bias = b1[e * H + hc * 32 + brow];
            #pragma unroll
            for (int r = 0; r < 4; ++r) {
                const int t = rb * 16 + kb * 4 + r;
                const float vvf = accH[r] + bias;
                const float g = 0.5f * vvf * (1.0f + erff(vvf * 0.70710678118654752f));
                Hs[cur][t * 40 + brow] = f2bf(g);
            }
        }

        // ---- stage 2 (chunk hc-1): accYt += W2^T-tiles @ H^T from [nxt] buffers ----
        if (hc > 0) {
            s16x8 bfrag[2];
            #pragma unroll
            for (int tg = 0; tg < 2; ++tg)
                bfrag[tg] = *reinterpret_cast<const s16x8*>(
                    &Hs[nxt][((tpart * 2 + tg) * 16 + mrow) * 40 + kb * 8]);
            #pragma unroll
            for (int db = 0; db < 4; ++db) {
                const int d = (dpart * 4 + db) * 16 + mrow;
                s16x8 afrag = *reinterpret_cast<const s16x8*>(
                    &W2s[nxt][d * 32 + ((kb ^ key4) << 3)]);
                #pragma unroll
                for (int tg = 0; tg < 2; ++tg)
                    accYt[tg][db] = __builtin_amdgcn_mfma_f32_16x16x32_bf16(
                        afrag, bfrag[tg], accYt[tg][db], 0, 0, 0);
            }
        }
        __syncthreads();       // single barrier per chunk
    }

    // final stage 2 for chunk 31 (buffers parity 1, written in iter 31, barrier done)
    {
        s16x8 bfrag[2];
        #pragma unroll
        for (int tg = 0; tg < 2; ++tg)
            bfrag[tg] = *reinterpret_cast<const s16x8*>(
                &Hs[1][((tpart * 2 + tg) * 16 + mrow) * 40 + kb * 8]);
        #pragma unroll
        for (int db = 0; db < 4; ++db) {
            const int d = (dpart * 4 + db) * 16 + mrow;
            s16x8 afrag = *reinterpret_cast<const s16x8*>(
                &W2s[1][d * 32 + ((kb ^ key4) << 3)]);
            #pragma unroll
            for (int tg = 0; tg < 2; ++tg)
                accYt[tg][db] = __builtin_amdgcn_mfma_f32_16x16x32_bf16(
                    afrag, bfrag[tg], accYt[tg][db], 0, 0, 0);
        }
    }

    // epilogue: out[t][d] += w * (y + b2), fp32 atomics
    #pragma unroll
    for (int tg = 0; tg < 2; ++tg) {
        const int tloc = (tpart * 2 + tg) * 16 + mrow;
        if (tloc < nvalid) {
            const float wt = wgts[tloc];
            float* obase = out + (size_t)toks[tloc] * D;
            #pragma unroll
            for (int db = 0; db < 4; ++db) {
                const int d0 = (dpart * 4 + db) * 16 + kb * 4;
                const float4 bv = *reinterpret_cast<const float4*>(b2 + e * D + d0);
                atomicAdd(obase + d0 + 0, (accYt[tg][db][0] + bv.x) * wt);
                atomicAdd(obase + d0 + 1, (accYt[tg][db][1] + bv.y) * wt);
                atomicAdd(obase + d0 + 2, (accYt[tg][db][2] + bv.z) * wt);
                atomicAdd(obase + d0 + 3, (accYt[tg][db][3] + bv.w) * wt);
            }
        }
    }
    #undef LOADW1
    #undef STOREW1
    #undef LOADW2
    #undef STOREW2
}

// ---------------- fallback expert FFN (fp32 weights, 256 thr) — used if ws too small ----------------
__global__ void __launch_bounds__(256) expert_kernel_fp32(
    const float* __restrict__ x, const float* __restrict__ w1, const float* __restrict__ w2,
    const float* __restrict__ b1, const float* __restrict__ b2,
    const int* __restrict__ cnt, const int* __restrict__ list, const float* __restrict__ wlist,
    float* __restrict__ out)
{
    const int e = blockIdx.y;
    int n = cnt[e]; n = (n < 0) ? 0 : ((n > NTOK) ? NTOK : n);
    const int tile0 = blockIdx.x * 64;
    if (tile0 >= n) return;
    const int nvalid = (n - tile0 < 64) ? (n - tile0) : 64;

    __shared__ __align__(16) unsigned short Xs [64 * 264];
    __shared__ __align__(16) unsigned short W1s[64 * 264];
    __shared__ __align__(16) unsigned short W2s[256 * 72];
    __shared__ __align__(16) unsigned short Hs [64 * 72];
    __shared__ int   toks[64];
    __shared__ float wgts[64];

    const int tid = threadIdx.x, lane = tid & 63, wv = tid >> 6;
    const int mrow = lane & 15, kb = lane >> 4;

    if (tid < 64) {
        if (tid < nvalid) {
            toks[tid] = list[e * NTOK + tile0 + tid] & 0x3FFF;
            wgts[tid] = wlist[e * NTOK + tile0 + tid];
        } else { toks[tid] = 0; wgts[tid] = 0.f; }
    }
    __syncthreads();

    #pragma unroll
    for (int r = 0; r < 8; ++r) {
        int v = r * 256 + tid, row = v >> 5, c8 = v & 31;
        s16x8 val = {0,0,0,0,0,0,0,0};
        if (row < nvalid) {
            const float* src = x + (size_t)toks[row] * D + c8 * 8;
            val = pack8(*reinterpret_cast<const float4*>(src),
                        *reinterpret_cast<const float4*>(src + 4));
        }
        *reinterpret_cast<s16x8*>(&Xs[row * 264 + c8 * 8]) = val;
    }

    f32x4 accYt[16];
    #pragma unroll
    for (int i = 0; i < 16; ++i) accYt[i] = (f32x4){0.f, 0.f, 0.f, 0.f};

    const int wr2 = wv >> 1, wc2 = wv & 1;
    const int hgrp = tid & 7, dblk = tid >> 3;
    const int dgrp = tid & 31, hblk8 = tid >> 5;

    for (int hc = 0; hc < 16; ++hc) {
        __syncthreads();
        {
            s16x8 Y8[8];
            #pragma unroll
            for (int i = 0; i < 8; ++i) {
                const float* src = w1 + ((size_t)(e * D + dblk * 8 + i)) * H + hc * 64 + hgrp * 8;
                Y8[i] = pack8(*reinterpret_cast<const float4*>(src),
                              *reinterpret_cast<const float4*>(src + 4));
            }
            #pragma unroll
            for (int j = 0; j < 8; ++j) {
                s16x8 V;
                #pragma unroll
                for (int i = 0; i < 8; ++i) V[i] = Y8[i][j];
                *reinterpret_cast<s16x8*>(&W1s[(hgrp * 8 + j) * 264 + dblk * 8]) = V;
            }
        }
        {
            s16x8 Z8[8];
            #pragma unroll
            for (int i = 0; i < 8; ++i) {
                const float* src = w2 + ((size_t)(e * H + hc * 64 + hblk8 * 8 + i)) * D + dgrp * 8;
                Z8[i] = pack8(*reinterpret_cast<const float4*>(src),
                              *reinterpret_cast<const float4*>(src + 4));
            }
            const int hswz = (hblk8 ^ (dgrp & 7)) << 3;
            #pragma unroll
            for (int j = 0; j < 8; ++j) {
                s16x8 V;
                #pragma unroll
                for (int i = 0; i < 8; ++i) V[i] = Z8[i][j];
                *reinterpret_cast<s16x8*>(&W2s[(dgrp * 8 + j) * 72 + hswz]) = V;
            }
        }
        __syncthreads();

        f32x4 accH[2][2];
        #pragma unroll
        for (int i = 0; i < 2; ++i)
            #pragma unroll
            for (int j = 0; j < 2; ++j) accH[i][j] = (f32x4){0.f, 0.f, 0.f, 0.f};
        #pragma unroll
        for (int ks = 0; ks < 8; ++ks) {
            const int koff = ks * 32 + kb * 8;
            s16x8 a0 = *reinterpret_cast<const s16x8*>(&Xs [((wr2*2+0)*16 + mrow)*264 + koff]);
            s16x8 a1 = *reinterpret_cast<const s16x8*>(&Xs [((wr2*2+1)*16 + mrow)*264 + koff]);
            s16x8 b0 = *reinterpret_cast<const s16x8*>(&W1s[((wc2*2+0)*16 + mrow)*264 + koff]);
            s16x8 b1v= *reinterpret_cast<const s16x8*>(&W1s[((wc2*2+1)*16 + mrow)*264 + koff]);
            accH[0][0] = __builtin_amdgcn_mfma_f32_16x16x32_bf16(a0, b0,  accH[0][0], 0, 0, 0);
            accH[0][1] = __builtin_amdgcn_mfma_f32_16x16x32_bf16(a0, b1v, accH[0][1], 0, 0, 0);
            accH[1][0] = __builtin_amdgcn_mfma_f32_16x16x32_bf16(a1, b0,  accH[1][0], 0, 0, 0);
            accH[1][1] = __builtin_amdgcn_mfma_f32_16x16x32_bf16(a1, b1v, accH[1][1], 0, 0, 0);
        }
        #pragma unroll
        for (int i = 0; i < 2; ++i)
            #pragma unroll
            for (int j = 0; j < 2; ++j) {
                const int hloc = (wc2*2 + j) * 16 + mrow;
                const float bias = b1[e * H + hc * 64 + hloc];
                #pragma unroll
                for (int r = 0; r < 4; ++r) {
                    const int m = (wr2*2 + i) * 16 + kb * 4 + r;
                    float vvf = accH[i][j][r] + bias;
                    float g = 0.5f * vvf * (1.0f + erff(vvf * 0.70710678118654752f));
                    Hs[m * 72 + hloc] = f2bf(g);
                }
            }
        __syncthreads();

        #pragma unroll
        for (int ks = 0; ks < 2; ++ks) {
            const int koff = ks * 32 + kb * 8;
            s16x8 bfrag = *reinterpret_cast<const s16x8*>(&Hs[(wv * 16 + mrow) * 72 + koff]);
            #pragma unroll
            for (int db = 0; db < 16; ++db) {
                const int arow = db * 16 + mrow;
                const int akey = (arow >> 3) & 7;
                s16x8 afrag = *reinterpret_cast<const s16x8*>(
                    &W2s[arow * 72 + (((ks * 4 + kb) ^ akey) << 3)]);
                accYt[db] = __builtin_amdgcn_mfma_f32_16x16x32_bf16(afrag, bfrag, accYt[db], 0, 0, 0);
            }
        }
    }

    {
        const int t = wv * 16 + mrow;
        if (t < nvalid) {
            const float wt = wgts[t];
            float* obase = out + (size_t)toks[t] * D;
            #pragma unroll
            for (int db = 0; db < 16; ++db) {
                const int d0 = db * 16 + kb * 4;
                #pragma unroll
                for (int r = 0; r < 4; ++r)
                    atomicAdd(obase + d0 + r, (accYt[db][r] + b2[e * D + d0 + r]) * wt);
            }
        }
    }
}

extern "C" void kernel_launch(void* const* d_in, const int* in_sizes, int n_in,
                              void* d_out, int out_size, void* d_ws, size_t ws_size,
                              hipStream_t stream)
{
    const float* x  = (const float*)d_in[0];
    const float* wr = (const float*)d_in[1];
    const float* br = (const float*)d_in[2];
    const float* w1 = (const float*)d_in[3];
    const float* b1 = (const float*)d_in[4];
    const float* w2 = (const float*)d_in[5];
    const float* b2 = (const float*)d_in[6];
    float* out = (float*)d_out;                 // [NTOK][D] fp32, then [NTOK][E] fp32 probs

    char* ws = (char*)d_ws;
    int*   cnt   = (int*)ws;                    //       256 B
    int*   list  = (int*)(ws + 256);            //   524,288 B  [E][NTOK]
    float* wlist = (float*)(ws + 524544);       //   524,288 B  [E][NTOK]
    unsigned short* w1t = (unsigned short*)(ws + 1048832);   // 4,194,304 B [E][H][D] bf16
    unsigned short* w2t = (unsigned short*)(ws + 5243136);   // 4,194,304 B [E][D][H] bf16
    const bool big = ws_size >= 9437440;        // deterministic across calls -> graph-safe

    hipMemsetAsync(out, 0, (size_t)NTOK * D * 4, stream);
    hipMemsetAsync(cnt, 0, 256, stream);
    if (big)
        convert_kernel<<<4096, 256, 0, stream>>>(w1, w2, w1t, w2t);
    router_kernel<<<NTOK / 64, 1024, 0, stream>>>(x, wr, br, out + (size_t)NTOK * D, cnt, list, wlist);
    if (big)
        expert_kernel_v4<<<dim3(256, 8), 512, 0, stream>>>(x, w1t, w2t, b1, b2, cnt, list, wlist, out);
    else
        expert_kernel_fp32<<<dim3(256, 8), 256, 0, stream>>>(x, w1, w2, b1, b2, cnt, list, wlist, out);
}

// Round 9
// 219.373 us; speedup vs baseline: 2.4348x; 1.2860x over previous
//
#include <hip/hip_runtime.h>

typedef float f32x4 __attribute__((ext_vector_type(4)));
typedef short s16x8 __attribute__((ext_vector_type(8)));

static constexpr int NTOK = 16384;   // B*S
static constexpr int D    = 256;
static constexpr int H    = 1024;
static constexpr int E    = 8;

__device__ __forceinline__ float bf2f(unsigned short u) {
    return __uint_as_float(((unsigned int)u) << 16);
}
__device__ __forceinline__ unsigned short f2bf(float f) {
    unsigned int u = __float_as_uint(f);
    u += 0x7FFFu + ((u >> 16) & 1u);   // round-to-nearest-even
    return (unsigned short)(u >> 16);
}
__device__ __forceinline__ s16x8 pack8(float4 a, float4 b) {
    s16x8 v;
    v[0] = (short)f2bf(a.x); v[1] = (short)f2bf(a.y);
    v[2] = (short)f2bf(a.z); v[3] = (short)f2bf(a.w);
    v[4] = (short)f2bf(b.x); v[5] = (short)f2bf(b.y);
    v[6] = (short)f2bf(b.z); v[7] = (short)f2bf(b.w);
    return v;
}

// ---------------- one-time weight convert+transpose: fp32 -> bf16 ----------------
__global__ void __launch_bounds__(256) convert_kernel(
    const float* __restrict__ w1, const float* __restrict__ w2,
    unsigned short* __restrict__ w1t, unsigned short* __restrict__ w2t)
{
    __shared__ unsigned short tile[32][33];
    int b = blockIdx.x;
    const float* src; unsigned short* dst;
    int Rr, Cc, tr, tc;
    if (b < 2048) {                      // w1: [256][1024] per expert
        int e = b >> 8, tt = b & 255;
        Rr = 256; Cc = 1024; tr = tt >> 5; tc = tt & 31;
        src = w1 + (size_t)e * Rr * Cc; dst = w1t + (size_t)e * Rr * Cc;
    } else {                             // w2: [1024][256] per expert
        b -= 2048;
        int e = b >> 8, tt = b & 255;
        Rr = 1024; Cc = 256; tr = tt >> 3; tc = tt & 7;
        src = w2 + (size_t)e * Rr * Cc; dst = w2t + (size_t)e * Rr * Cc;
    }
    const int tid = threadIdx.x;
    const int c = tid & 31, r0 = tid >> 5;
    #pragma unroll
    for (int rr = 0; rr < 32; rr += 8)
        tile[r0 + rr][c] = f2bf(src[(size_t)(tr * 32 + r0 + rr) * Cc + tc * 32 + c]);
    __syncthreads();
    #pragma unroll
    for (int rr = 0; rr < 32; rr += 8)
        dst[(size_t)(tc * 32 + r0 + rr) * Rr + tr * 32 + c] = tile[c][r0 + rr];
}

// ---------------- router: 16 lanes/token, block-aggregated atomics, slot-tagged lists ----------------
__global__ void __launch_bounds__(1024) router_kernel(
    const float* __restrict__ x,          // [NTOK][D] fp32
    const float* __restrict__ wr,         // [D][E]    fp32
    const float* __restrict__ br,         // [E]       fp32
    float* __restrict__ probs_out,        // [NTOK][E] fp32
    int* __restrict__ cnt, int* __restrict__ list, float* __restrict__ wlist)
{
    __shared__ float wrs[D][9];
    __shared__ int lcnt[8];
    __shared__ int gbase[8];
    const int tid = threadIdx.x;
    if (tid < 256) {
        float4 a = *reinterpret_cast<const float4*>(wr + tid * 8);
        float4 b = *reinterpret_cast<const float4*>(wr + tid * 8 + 4);
        wrs[tid][0] = a.x; wrs[tid][1] = a.y; wrs[tid][2] = a.z; wrs[tid][3] = a.w;
        wrs[tid][4] = b.x; wrs[tid][5] = b.y; wrs[tid][6] = b.z; wrs[tid][7] = b.w;
    }
    if (tid < 8) lcnt[tid] = 0;
    __syncthreads();

    const int g = tid >> 4, l = tid & 15;            // 64 tokens/block, 16 lanes/token
    const int t = blockIdx.x * 64 + g;

    float lg[8];
    #pragma unroll
    for (int e = 0; e < 8; ++e) lg[e] = 0.f;

    const float* xr = x + (size_t)t * D;
    #pragma unroll
    for (int r = 0; r < 4; ++r) {
        const int d = r * 64 + l * 4;
        float4 xv = *reinterpret_cast<const float4*>(xr + d);
        #pragma unroll
        for (int j = 0; j < 4; ++j) {
            const float xf = (j == 0) ? xv.x : (j == 1) ? xv.y : (j == 2) ? xv.z : xv.w;
            #pragma unroll
            for (int e = 0; e < 8; ++e) lg[e] += xf * wrs[d + j][e];
        }
    }
    #pragma unroll
    for (int off = 1; off < 16; off <<= 1)
        #pragma unroll
        for (int e = 0; e < 8; ++e) lg[e] += __shfl_xor(lg[e], off, 16);

    int i1 = 0, i2 = 0, lp1 = 0, lp2 = 0;
    float wa = 0.f, wb = 0.f;
    if (l == 0) {
        #pragma unroll
        for (int e = 0; e < 8; ++e) lg[e] += br[e];
        float mx = lg[0];
        #pragma unroll
        for (int e = 1; e < 8; ++e) mx = fmaxf(mx, lg[e]);
        float p[8], s = 0.f;
        #pragma unroll
        for (int e = 0; e < 8; ++e) { p[e] = expf(lg[e] - mx); s += p[e]; }
        const float inv = 1.f / s;
        #pragma unroll
        for (int e = 0; e < 8; ++e) p[e] *= inv;
        float4 o0 = {p[0], p[1], p[2], p[3]}, o1 = {p[4], p[5], p[6], p[7]};
        *reinterpret_cast<float4*>(probs_out + t * 8)     = o0;
        *reinterpret_cast<float4*>(probs_out + t * 8 + 4) = o1;

        #pragma unroll
        for (int e = 1; e < 8; ++e) if (p[e] > p[i1]) i1 = e;   // strict > : lowest index wins
        i2 = (i1 == 0) ? 1 : 0;
        #pragma unroll
        for (int e = 0; e < 8; ++e) if (e != i1 && p[e] > p[i2]) i2 = e;
        const float sw = p[i1] + p[i2];
        wa = p[i1] / sw; wb = p[i2] / sw;
        lp1 = atomicAdd(&lcnt[i1], 1);
        lp2 = atomicAdd(&lcnt[i2], 1);
    }
    __syncthreads();
    if (tid < 8) gbase[tid] = atomicAdd(&cnt[tid], lcnt[tid]);   // 8 global atomics/block
    __syncthreads();
    if (l == 0) {
        int pos = gbase[i1] + lp1;
        list[i1 * NTOK + pos] = t;                // slot k=0
        wlist[i1 * NTOK + pos] = wa;
        pos = gbase[i2] + lp2;
        list[i2 * NTOK + pos] = t | (1 << 30);    // slot k=1
        wlist[i2 * NTOK + pos] = wb;
    }
}

// ---------------- expert FFN v5: r8 K-loop + mode-selected epilogue ----------------
// mode 0: atomicAdd into out (r8 behavior)  |  mode 1: fp32 slot stores  |  mode 2: bf16 slot stores
__global__ void __launch_bounds__(512, 4) expert_kernel_v5(
    const float* __restrict__ x,              // [NTOK][D] fp32
    const unsigned short* __restrict__ w1t,   // [E][H][D] bf16
    const unsigned short* __restrict__ w2t,   // [E][D][H] bf16
    const float* __restrict__ b1,             // [E][H]
    const float* __restrict__ b2,             // [E][D]
    const int* __restrict__ cnt, const int* __restrict__ list,
    const float* __restrict__ wlist,
    float* __restrict__ out,                  // [NTOK][D] fp32 (zeroed, mode 0 only)
    float* __restrict__ ybuf32,               // [2][NTOK][D] fp32 (mode 1)
    unsigned short* __restrict__ ybuf16,      // [2][NTOK][D] bf16 (mode 2)
    const int mode)
{
    const int e = blockIdx.y;
    int n = cnt[e]; n = (n < 0) ? 0 : ((n > NTOK) ? NTOK : n);
    const int tile0 = blockIdx.x * 64;
    if (tile0 >= n) return;
    const int nvalid = (n - tile0 < 64) ? (n - tile0) : 64;

    __shared__ __align__(16) unsigned short W1s[2][32 * 264];  // [h][d+8]  pad
    __shared__ __align__(16) unsigned short W2s[2][256 * 32];  // [d][h]    XOR-swizzled
    __shared__ __align__(16) unsigned short Hs [2][64 * 40];   // [t][h+8]  pad
    __shared__ int   toks[64];                                  // raw entries (bit30 = slot)
    __shared__ float wgts[64];

    const int tid  = threadIdx.x;
    const int lane = tid & 63;
    const int wv   = tid >> 6;          // 0..7
    const int mrow = lane & 15;
    const int kb   = lane >> 4;         // 0..3
    const int key4 = (mrow & 3) ^ ((mrow >> 2) & 3);   // W2s read swizzle key
    const int rb    = wv & 3;           // stage1 token block
    const int chb   = wv >> 2;          // stage1 h half
    const int tpart = wv & 1;           // stage2 token half
    const int dpart = wv >> 1;          // stage2 d quarter

    if (tid < 64) {
        if (tid < nvalid) {
            toks[tid] = list[e * NTOK + tile0 + tid];
            wgts[tid] = wlist[e * NTOK + tile0 + tid];
        } else { toks[tid] = 0; wgts[tid] = 0.f; }
    }

    const size_t w1b = (size_t)e * H * D;
    const size_t w2b = (size_t)e * D * H;
    s16x8 pfW1[2], pfW2[2];

    #define LOADW1(HC)                                                                  \
        _Pragma("unroll")                                                               \
        for (int k = 0; k < 2; ++k) {                                                   \
            const int s = k * 512 + tid, h1 = s >> 5, c1 = s & 31;                      \
            pfW1[k] = *reinterpret_cast<const s16x8*>(                                  \
                w1t + w1b + (size_t)((HC) * 32 + h1) * D + c1 * 8);                     \
        }
    #define STOREW1(BUF)                                                                \
        _Pragma("unroll")                                                               \
        for (int k = 0; k < 2; ++k) {                                                   \
            const int s = k * 512 + tid, h1 = s >> 5, c1 = s & 31;                      \
            *reinterpret_cast<s16x8*>(&W1s[BUF][h1 * 264 + c1 * 8]) = pfW1[k];          \
        }
    #define LOADW2(HC)                                                                  \
        _Pragma("unroll")                                                               \
        for (int k = 0; k < 2; ++k) {                                                   \
            const int s = k * 512 + tid, d2 = s >> 2, c2 = s & 3;                       \
            pfW2[k] = *reinterpret_cast<const s16x8*>(                                  \
                w2t + w2b + (size_t)d2 * H + (HC) * 32 + c2 * 8);                       \
        }
    #define STOREW2(BUF)                                                                \
        _Pragma("unroll")                                                               \
        for (int k = 0; k < 2; ++k) {                                                   \
            const int s = k * 512 + tid, d2 = s >> 2, c2 = s & 3;                       \
            const int k2 = (d2 & 3) ^ ((d2 >> 2) & 3);                                  \
            *reinterpret_cast<s16x8*>(&W2s[BUF][d2 * 32 + ((c2 ^ k2) << 3)]) = pfW2[k]; \
        }

    LOADW1(0);
    __syncthreads();           // toks visible

    // A-fragments in registers: token row rb*16+mrow, full K=256
    s16x8 aFrag[8];
    {
        const float* xrow = x + (size_t)(toks[rb * 16 + mrow] & 0x3FFF) * D;
        #pragma unroll
        for (int ks = 0; ks < 8; ++ks) {
            const float* src = xrow + ks * 32 + kb * 8;
            aFrag[ks] = pack8(*reinterpret_cast<const float4*>(src),
                              *reinterpret_cast<const float4*>(src + 4));
        }
    }

    STOREW1(0);
    LOADW1(1);
    LOADW2(0);
    __syncthreads();           // W1s[0] visible

    f32x4 accYt[2][4];         // [tg][db]: t=(tpart*2+tg)*16+mrow, d=(dpart*4+db)*16+kb*4+r
    #pragma unroll
    for (int i = 0; i < 2; ++i)
        #pragma unroll
        for (int j = 0; j < 4; ++j) accYt[i][j] = (f32x4){0.f, 0.f, 0.f, 0.f};

    for (int hc = 0; hc < 32; ++hc) {
        const int cur = hc & 1, nxt = cur ^ 1;

        if (hc < 31) { STOREW1(nxt); }
        if (hc < 30) { LOADW1(hc + 2); }
        STOREW2(cur);
        if (hc < 31) { LOADW2(hc + 1); }

        // ---- stage 1 (chunk hc): H = gelu(X @ W1 + b1) -> Hs[cur] ----
        f32x4 accH = (f32x4){0.f, 0.f, 0.f, 0.f};
        {
            const int brow = chb * 16 + mrow;
            #pragma unroll
            for (int ks = 0; ks < 8; ++ks) {
                s16x8 bfrag = *reinterpret_cast<const s16x8*>(
                    &W1s[cur][brow * 264 + ks * 32 + kb * 8]);
                accH = __builtin_amdgcn_mfma_f32_16x16x32_bf16(aFrag[ks], bfrag, accH, 0, 0, 0);
            }
            const float bias = b1[e * H + hc * 32 + brow];
            #pragma unroll
            for (int r = 0; r < 4; ++r) {
                const int t = rb * 16 + kb * 4 + r;
                const float vvf = accH[r] + bias;
                const float g = 0.5f * vvf * (1.0f + erff(vvf * 0.70710678118654752f));
                Hs[cur][t * 40 + brow] = f2bf(g);
            }
        }

        // ---- stage 2 (chunk hc-1): accYt += W2^T-tiles @ H^T from [nxt] buffers ----
        if (hc > 0) {
            s16x8 bfrag[2];
            #pragma unroll
            for (int tg = 0; tg < 2; ++tg)
                bfrag[tg] = *reinterpret_cast<const s16x8*>(
                    &Hs[nxt][((tpart * 2 + tg) * 16 + mrow) * 40 + kb * 8]);
            #pragma unroll
            for (int db = 0; db < 4; ++db) {
                const int d = (dpart * 4 + db) * 16 + mrow;
                s16x8 afrag = *reinterpret_cast<const s16x8*>(
                    &W2s[nxt][d * 32 + ((kb ^ key4) << 3)]);
                #pragma unroll
                for (int tg = 0; tg < 2; ++tg)
                    accYt[tg][db] = __builtin_amdgcn_mfma_f32_16x16x32_bf16(
                        afrag, bfrag[tg], accYt[tg][db], 0, 0, 0);
            }
        }
        __syncthreads();       // single barrier per chunk
    }

    // final stage 2 for chunk 31
    {
        s16x8 bfrag[2];
        #pragma unroll
        for (int tg = 0; tg < 2; ++tg)
            bfrag[tg] = *reinterpret_cast<const s16x8*>(
                &Hs[1][((tpart * 2 + tg) * 16 + mrow) * 40 + kb * 8]);
        #pragma unroll
        for (int db = 0; db < 4; ++db) {
            const int d = (dpart * 4 + db) * 16 + mrow;
            s16x8 afrag = *reinterpret_cast<const s16x8*>(
                &W2s[1][d * 32 + ((kb ^ key4) << 3)]);
            #pragma unroll
            for (int tg = 0; tg < 2; ++tg)
                accYt[tg][db] = __builtin_amdgcn_mfma_f32_16x16x32_bf16(
                    afrag, bfrag[tg], accYt[tg][db], 0, 0, 0);
        }
    }

    // epilogue: v = w * (y + b2) -> slot stores (mode 1/2) or atomics (mode 0)
    #pragma unroll
    for (int tg = 0; tg < 2; ++tg) {
        const int tloc = (tpart * 2 + tg) * 16 + mrow;
        if (tloc < nvalid) {
            const float wt = wgts[tloc];
            const int raw = toks[tloc];
            const int t = raw & 0x3FFF;
            const size_t slotbase = ((size_t)((raw >> 30) & 1) * NTOK + t) * D;
            if (mode == 1) {
                float* ybase = ybuf32 + slotbase;
                #pragma unroll
                for (int db = 0; db < 4; ++db) {
                    const int d0 = (dpart * 4 + db) * 16 + kb * 4;
                    const float4 bv = *reinterpret_cast<const float4*>(b2 + e * D + d0);
                    float4 v = {(accYt[tg][db][0] + bv.x) * wt, (accYt[tg][db][1] + bv.y) * wt,
                                (accYt[tg][db][2] + bv.z) * wt, (accYt[tg][db][3] + bv.w) * wt};
                    *reinterpret_cast<float4*>(ybase + d0) = v;
                }
            } else if (mode == 2) {
                unsigned short* ybase = ybuf16 + slotbase;
                #pragma unroll
                for (int db = 0; db < 4; ++db) {
                    const int d0 = (dpart * 4 + db) * 16 + kb * 4;
                    const float4 bv = *reinterpret_cast<const float4*>(b2 + e * D + d0);
                    ushort4 v;
                    v.x = f2bf((accYt[tg][db][0] + bv.x) * wt);
                    v.y = f2bf((accYt[tg][db][1] + bv.y) * wt);
                    v.z = f2bf((accYt[tg][db][2] + bv.z) * wt);
                    v.w = f2bf((accYt[tg][db][3] + bv.w) * wt);
                    *reinterpret_cast<ushort4*>(ybase + d0) = v;
                }
            } else {
                float* obase = out + (size_t)t * D;
                #pragma unroll
                for (int db = 0; db < 4; ++db) {
                    const int d0 = (dpart * 4 + db) * 16 + kb * 4;
                    const float4 bv = *reinterpret_cast<const float4*>(b2 + e * D + d0);
                    atomicAdd(obase + d0 + 0, (accYt[tg][db][0] + bv.x) * wt);
                    atomicAdd(obase + d0 + 1, (accYt[tg][db][1] + bv.y) * wt);
                    atomicAdd(obase + d0 + 2, (accYt[tg][db][2] + bv.z) * wt);
                    atomicAdd(obase + d0 + 3, (accYt[tg][db][3] + bv.w) * wt);
                }
            }
        }
    }
    #undef LOADW1
    #undef STOREW1
    #undef LOADW2
    #undef STOREW2
}

// ---------------- combine: out = ybuf[0] + ybuf[1] ----------------
__global__ void __launch_bounds__(256) combine_f32_kernel(
    const float* __restrict__ ybuf, float* __restrict__ out)
{
    const size_t i = ((size_t)blockIdx.x * 256 + threadIdx.x) * 4;
    float4 a = *reinterpret_cast<const float4*>(ybuf + i);
    float4 b = *reinterpret_cast<const float4*>(ybuf + (size_t)NTOK * D + i);
    float4 v = {a.x + b.x, a.y + b.y, a.z + b.z, a.w + b.w};
    *reinterpret_cast<float4*>(out + i) = v;
}
__global__ void __launch_bounds__(256) combine_bf16_kernel(
    const unsigned short* __restrict__ ybuf, float* __restrict__ out)
{
    const size_t i = ((size_t)blockIdx.x * 256 + threadIdx.x) * 4;
    ushort4 a = *reinterpret_cast<const ushort4*>(ybuf + i);
    ushort4 b = *reinterpret_cast<const ushort4*>(ybuf + (size_t)NTOK * D + i);
    float4 v = {bf2f(a.x) + bf2f(b.x), bf2f(a.y) + bf2f(b.y),
                bf2f(a.z) + bf2f(b.z), bf2f(a.w) + bf2f(b.w)};
    *reinterpret_cast<float4*>(out + i) = v;
}

// ---------------- fallback expert FFN (fp32 weights, 256 thr) — used if ws too small ----------------
__global__ void __launch_bounds__(256) expert_kernel_fp32(
    const float* __restrict__ x, const float* __restrict__ w1, const float* __restrict__ w2,
    const float* __restrict__ b1, const float* __restrict__ b2,
    const int* __restrict__ cnt, const int* __restrict__ list, const float* __restrict__ wlist,
    float* __restrict__ out)
{
    const int e = blockIdx.y;
    int n = cnt[e]; n = (n < 0) ? 0 : ((n > NTOK) ? NTOK : n);
    const int tile0 = blockIdx.x * 64;
    if (tile0 >= n) return;
    const int nvalid = (n - tile0 < 64) ? (n - tile0) : 64;

    __shared__ __align__(16) unsigned short Xs [64 * 264];
    __shared__ __align__(16) unsigned short W1s[64 * 264];
    __shared__ __align__(16) unsigned short W2s[256 * 72];
    __shared__ __align__(16) unsigned short Hs [64 * 72];
    __shared__ int   toks[64];
    __shared__ float wgts[64];

    const int tid = threadIdx.x, lane = tid & 63, wv = tid >> 6;
    const int mrow = lane & 15, kb = lane >> 4;

    if (tid < 64) {
        if (tid < nvalid) {
            toks[tid] = list[e * NTOK + tile0 + tid] & 0x3FFF;
            wgts[tid] = wlist[e * NTOK + tile0 + tid];
        } else { toks[tid] = 0; wgts[tid] = 0.f; }
    }
    __syncthreads();

    #pragma unroll
    for (int r = 0; r < 8; ++r) {
        int v = r * 256 + tid, row = v >> 5, c8 = v & 31;
        s16x8 val = {0,0,0,0,0,0,0,0};
        if (row < nvalid) {
            const float* src = x + (size_t)toks[row] * D + c8 * 8;
            val = pack8(*reinterpret_cast<const float4*>(src),
                        *reinterpret_cast<const float4*>(src + 4));
        }
        *reinterpret_cast<s16x8*>(&Xs[row * 264 + c8 * 8]) = val;
    }

    f32x4 accYt[16];
    #pragma unroll
    for (int i = 0; i < 16; ++i) accYt[i] = (f32x4){0.f, 0.f, 0.f, 0.f};

    const int wr2 = wv >> 1, wc2 = wv & 1;
    const int hgrp = tid & 7, dblk = tid >> 3;
    const int dgrp = tid & 31, hblk8 = tid >> 5;

    for (int hc = 0; hc < 16; ++hc) {
        __syncthreads();
        {
            s16x8 Y8[8];
            #pragma unroll
            for (int i = 0; i < 8; ++i) {
                const float* src = w1 + ((size_t)(e * D + dblk * 8 + i)) * H + hc * 64 + hgrp * 8;
                Y8[i] = pack8(*reinterpret_cast<const float4*>(src),
                              *reinterpret_cast<const float4*>(src + 4));
            }
            #pragma unroll
            for (int j = 0; j < 8; ++j) {
                s16x8 V;
                #pragma unroll
                for (int i = 0; i < 8; ++i) V[i] = Y8[i][j];
                *reinterpret_cast<s16x8*>(&W1s[(hgrp * 8 + j) * 264 + dblk * 8]) = V;
            }
        }
        {
            s16x8 Z8[8];
            #pragma unroll
            for (int i = 0; i < 8; ++i) {
                const float* src = w2 + ((size_t)(e * H + hc * 64 + hblk8 * 8 + i)) * D + dgrp * 8;
                Z8[i] = pack8(*reinterpret_cast<const float4*>(src),
                              *reinterpret_cast<const float4*>(src + 4));
            }
            const int hswz = (hblk8 ^ (dgrp & 7)) << 3;
            #pragma unroll
            for (int j = 0; j < 8; ++j) {
                s16x8 V;
                #pragma unroll
                for (int i = 0; i < 8; ++i) V[i] = Z8[i][j];
                *reinterpret_cast<s16x8*>(&W2s[(dgrp * 8 + j) * 72 + hswz]) = V;
            }
        }
        __syncthreads();

        f32x4 accH[2][2];
        #pragma unroll
        for (int i = 0; i < 2; ++i)
            #pragma unroll
            for (int j = 0; j < 2; ++j) accH[i][j] = (f32x4){0.f, 0.f, 0.f, 0.f};
        #pragma unroll
        for (int ks = 0; ks < 8; ++ks) {
            const int koff = ks * 32 + kb * 8;
            s16x8 a0 = *reinterpret_cast<const s16x8*>(&Xs [((wr2*2+0)*16 + mrow)*264 + koff]);
            s16x8 a1 = *reinterpret_cast<const s16x8*>(&Xs [((wr2*2+1)*16 + mrow)*264 + koff]);
            s16x8 b0 = *reinterpret_cast<const s16x8*>(&W1s[((wc2*2+0)*16 + mrow)*264 + koff]);
            s16x8 b1v= *reinterpret_cast<const s16x8*>(&W1s[((wc2*2+1)*16 + mrow)*264 + koff]);
            accH[0][0] = __builtin_amdgcn_mfma_f32_16x16x32_bf16(a0, b0,  accH[0][0], 0, 0, 0);
            accH[0][1] = __builtin_amdgcn_mfma_f32_16x16x32_bf16(a0, b1v, accH[0][1], 0, 0, 0);
            accH[1][0] = __builtin_amdgcn_mfma_f32_16x16x32_bf16(a1, b0,  accH[1][0], 0, 0, 0);
            accH[1][1] = __builtin_amdgcn_mfma_f32_16x16x32_bf16(a1, b1v, accH[1][1], 0, 0, 0);
        }
        #pragma unroll
        for (int i = 0; i < 2; ++i)
            #pragma unroll
            for (int j = 0; j < 2; ++j) {
                const int hloc = (wc2*2 + j) * 16 + mrow;
                const float bias = b1[e * H + hc * 64 + hloc];
                #pragma unroll
                for (int r = 0; r < 4; ++r) {
                    const int m = (wr2*2 + i) * 16 + kb * 4 + r;
                    float vvf = accH[i][j][r] + bias;
                    float g = 0.5f * vvf * (1.0f + erff(vvf * 0.70710678118654752f));
                    Hs[m * 72 + hloc] = f2bf(g);
                }
            }
        __syncthreads();

        #pragma unroll
        for (int ks = 0; ks < 2; ++ks) {
            const int koff = ks * 32 + kb * 8;
            s16x8 bfrag = *reinterpret_cast<const s16x8*>(&Hs[(wv * 16 + mrow) * 72 + koff]);
            #pragma unroll
            for (int db = 0; db < 16; ++db) {
                const int arow = db * 16 + mrow;
                const int akey = (arow >> 3) & 7;
                s16x8 afrag = *reinterpret_cast<const s16x8*>(
                    &W2s[arow * 72 + (((ks * 4 + kb) ^ akey) << 3)]);
                accYt[db] = __builtin_amdgcn_mfma_f32_16x16x32_bf16(afrag, bfrag, accYt[db], 0, 0, 0);
            }
        }
    }

    {
        const int t = wv * 16 + mrow;
        if (t < nvalid) {
            const float wt = wgts[t];
            float* obase = out + (size_t)toks[t] * D;
            #pragma unroll
            for (int db = 0; db < 16; ++db) {
                const int d0 = db * 16 + kb * 4;
                #pragma unroll
                for (int r = 0; r < 4; ++r)
                    atomicAdd(obase + d0 + r, (accYt[db][r] + b2[e * D + d0 + r]) * wt);
            }
        }
    }
}

extern "C" void kernel_launch(void* const* d_in, const int* in_sizes, int n_in,
                              void* d_out, int out_size, void* d_ws, size_t ws_size,
                              hipStream_t stream)
{
    const float* x  = (const float*)d_in[0];
    const float* wr = (const float*)d_in[1];
    const float* br = (const float*)d_in[2];
    const float* w1 = (const float*)d_in[3];
    const float* b1 = (const float*)d_in[4];
    const float* w2 = (const float*)d_in[5];
    const float* b2 = (const float*)d_in[6];
    float* out = (float*)d_out;                 // [NTOK][D] fp32, then [NTOK][E] fp32 probs

    char* ws = (char*)d_ws;
    int*   cnt   = (int*)ws;                    //       256 B
    int*   list  = (int*)(ws + 256);            //   524,288 B  [E][NTOK]
    float* wlist = (float*)(ws + 524544);       //   524,288 B  [E][NTOK]
    unsigned short* w1t = (unsigned short*)(ws + 1048832);   // 4,194,304 B [E][H][D] bf16
    unsigned short* w2t = (unsigned short*)(ws + 5243136);   // 4,194,304 B [E][D][H] bf16
    float*          ybuf32 = (float*)(ws + 9437440);          // 33,554,432 B (mode 1)
    unsigned short* ybuf16 = (unsigned short*)(ws + 9437440); // 16,777,216 B (mode 2)

    const bool big = ws_size >= 9437440;        // deterministic across calls -> graph-safe
    int mode = 0;
    if (big) {
        if (ws_size >= 9437440ull + 33554432ull)      mode = 1;   // fp32 slot stores
        else if (ws_size >= 9437440ull + 16777216ull) mode = 2;   // bf16 slot stores
    }

    if (mode == 0)
        hipMemsetAsync(out, 0, (size_t)NTOK * D * 4, stream);  // atomic path accumulates into out
    hipMemsetAsync(cnt, 0, 256, stream);
    if (big)
        convert_kernel<<<4096, 256, 0, stream>>>(w1, w2, w1t, w2t);
    router_kernel<<<NTOK / 64, 1024, 0, stream>>>(x, wr, br, out + (size_t)NTOK * D, cnt, list, wlist);
    if (big) {
        expert_kernel_v5<<<dim3(256, 8), 512, 0, stream>>>(
            x, w1t, w2t, b1, b2, cnt, list, wlist, out, ybuf32, ybuf16, mode);
        if (mode == 1)
            combine_f32_kernel<<<(NTOK * D / 4) / 256, 256, 0, stream>>>(ybuf32, out);
        else if (mode == 2)
            combine_bf16_kernel<<<(NTOK * D / 4) / 256, 256, 0, stream>>>(ybuf16, out);
    } else {
        expert_kernel_fp32<<<dim3(256, 8), 256, 0, stream>>>(x, w1, w2, b1, b2, cnt, list, wlist, out);
    }
}